// Round 7
// baseline (583.078 us; speedup 1.0000x reference)
//
#include <hip/hip_runtime.h>
#include <math.h>

#define NN 50000
#define NPAD 50048
#define EE 800000
#define HIDC 256
#define INCH 320

typedef __attribute__((ext_vector_type(8))) short bf16x8;
typedef __attribute__((ext_vector_type(4))) float f32x4;
typedef __attribute__((ext_vector_type(2))) float f32x2;

static __device__ __forceinline__ float4 ld4(const float* p){ return *(const float4*)p; }

static __device__ __forceinline__ unsigned short f2b(float f){
  union { float f; unsigned u; } v; v.f = f;
  unsigned r = v.u + 0x7fffu + ((v.u >> 16) & 1u);
  return (unsigned short)(r >> 16);
}
static __device__ __forceinline__ float b2f(unsigned short u){
  union { unsigned u; float f; } v; v.u = ((unsigned)u) << 16; return v.f;
}
static __device__ __forceinline__ float rlane_f(float v, int l){
  return __uint_as_float(__builtin_amdgcn_readlane(__float_as_uint(v), l));
}
static __device__ __forceinline__ int rlane_i(int v, int l){
  return __builtin_amdgcn_readlane(v, l);
}
// unpack two bf16 packed in a u32 -> 2 floats (lo = .x, hi = .y)
static __device__ __forceinline__ f32x2 unpk(unsigned u){
  f32x2 r;
  r.x = __uint_as_float(u << 16);
  r.y = __uint_as_float(u & 0xffff0000u);
  return r;
}
static __device__ __forceinline__ f32x2 fma2(f32x2 a, f32x2 b, f32x2 c){
  return __builtin_elementwise_fma(a, b, c);
}
static __device__ __forceinline__ f32x2 max2(f32x2 a, f32x2 b){
  return __builtin_elementwise_max(a, b);
}
static __device__ __forceinline__ f32x2 set2(float v){ f32x2 r; r.x = v; r.y = v; return r; }

typedef const __attribute__((address_space(1))) unsigned int* gas_u32;
typedef __attribute__((address_space(3))) unsigned int* las_u32;
static __device__ __forceinline__ void gload_lds16(const void* g, void* l){
  __builtin_amdgcn_global_load_lds((gas_u32)g, (las_u32)l, 16, 0, 0);
}

// ---------------- fused prep: cvt_x | node_mlp(+nuv, +deg=0) | cvt_w by blockIdx range ----------------
#define PREP_CVTX  12500            // 50000 rows x 64 lanes/row
#define PREP_MLP   196              // ceil(50000/256)
#define PREP_CVTW  1219             // 312064 threads
__global__ __launch_bounds__(256) void prep_kernel(
    const float* __restrict__ x, unsigned short* __restrict__ nodex,
    const float* __restrict__ kpts, const float* __restrict__ pts3d,
    const float* __restrict__ W1, const float* __restrict__ b1,
    const float* __restrict__ W2, const float* __restrict__ b2,
    float* __restrict__ nuv, int* __restrict__ deg,
    const float* __restrict__ Wres, const float* __restrict__ Wl,
    const float* __restrict__ Wr,  const float* __restrict__ Wp,
    const float* __restrict__ bres, const float* __restrict__ bl,
    const float* __restrict__ br,
    unsigned short* __restrict__ wt, float* __restrict__ biascat)
{
  int b = blockIdx.x;
  if (b < PREP_CVTX) {
    // ---- cvt_x: x fp32 -> nodex bf16 cols 0..255
    int t = b*256 + threadIdx.x;
    int row = t >> 6;
    int c4 = (t & 63) * 4;
    float4 v = ld4(x + (size_t)row*256 + c4);
    ushort4 o;
    o.x = f2b(v.x); o.y = f2b(v.y); o.z = f2b(v.z); o.w = f2b(v.w);
    *(ushort4*)(nodex + (size_t)row*320 + c4) = o;
  } else if (b < PREP_CVTX + PREP_MLP) {
    // ---- node_mlp: pos MLP -> nodex cols 256..319; also norm_uv table + deg=0
    int i = (b - PREP_CVTX)*256 + threadIdx.x;
    if (i >= NN) return;
    deg[i] = 0;
    float u = kpts[2*i]   * (1.0f/1216.0f);
    float v = kpts[2*i+1] * (1.0f/352.0f);
    float d = pts3d[3*i+2];
    float2 uv; uv.x = u; uv.y = v;
    *(float2*)(nuv + 2*i) = uv;
    float h[32];
#pragma unroll
    for (int j=0;j<32;++j){
      float t = u*W1[j] + v*W1[32+j] + d*W1[64+j] + b1[j];
      h[j] = t / (1.0f + __expf(-t));   // silu
    }
    for (int o=0;o<64;o+=4){
      float s0=b2[o], s1=b2[o+1], s2=b2[o+2], s3=b2[o+3];
#pragma unroll
      for (int j=0;j<32;++j){
        float hj = h[j];
        const float* w = W2 + j*64 + o;
        s0 += hj*w[0]; s1 += hj*w[1]; s2 += hj*w[2]; s3 += hj*w[3];
      }
      ushort4 r; r.x=f2b(s0); r.y=f2b(s1); r.z=f2b(s2); r.w=f2b(s3);
      *(ushort4*)(nodex + (size_t)i*320 + 256 + o) = r;
    }
  } else {
    // ---- cvt_w: transpose weights to bf16 N-major + bias concat
    int t = (b - PREP_CVTX - PREP_MLP)*256 + threadIdx.x;
    if (t < 245760) {
      int which = t / 81920;
      int rem = t % 81920;
      int n = rem / 320, k = rem % 320;
      const float* W = (which == 0) ? Wres : (which == 1) ? Wl : Wr;
      wt[(size_t)which*81920 + rem] = f2b(W[(size_t)k*256 + n]);
    } else if (t < 311296) {
      int r = t - 245760;
      int n = r / 256, k = r % 256;
      wt[245760 + r] = f2b(Wp[(size_t)k*256 + n]);
    } else if (t < 312064) {
      int r = t - 311296;   // 0..767
      const float* src = (r < 256) ? bres : (r < 512) ? bl : br;
      biascat[r] = src[r & 255];
    }
  }
}

// ---------------- bf16 MFMA GEMM: C(M,Nt) = A(M,K) @ BT(Nt,K)^T + bias ----------------
// GK=64 + XOR slot-swizzle; grid transposed (col-blocks fastest).
#define GK 64
__global__ __launch_bounds__(256) void mfma_gemm_kernel(
    const unsigned short* __restrict__ A,
    const unsigned short* __restrict__ BT,
    const float* __restrict__ bias,
    float* __restrict__ Cf,
    unsigned short* __restrict__ Cx1,
    unsigned short* __restrict__ Cx2,
    int M, int K)
{
  __shared__ unsigned short Als[128*GK];   // 16 KB
  __shared__ unsigned short Bls[128*GK];   // 16 KB
  int tid = threadIdx.x;
  int lane = tid & 63, wave = tid >> 6;
  int wm = (wave >> 1) * 64, wn = (wave & 1) * 64;
  int row0 = blockIdx.y * 128, col0 = blockIdx.x * 128;

  f32x4 acc[4][4];
#pragma unroll
  for (int i=0;i<4;++i)
#pragma unroll
    for (int j=0;j<4;++j){ acc[i][j].x=0.f; acc[i][j].y=0.f; acc[i][j].z=0.f; acc[i][j].w=0.f; }

  int fm = lane & 15;
  int q4 = lane >> 4;          // quarter-wave index 0..3

  for (int k0 = 0; k0 < K; k0 += GK) {
#pragma unroll
    for (int it = 0; it < 4; ++it) {
      int cgl = it*256 + tid;            // chunk id 0..1023 (16B chunks)
      int r = cgl >> 3;                  // tile row 0..127
      int kb = ((cgl ^ r) & 7) * 8;      // swizzled k-chunk (elements)
      gload_lds16(A  + (size_t)(row0 + r)*K + k0 + kb, Als + (it*256 + wave*64)*8);
      gload_lds16(BT + (size_t)(col0 + r)*K + k0 + kb, Bls + (it*256 + wave*64)*8);
    }
    __syncthreads();

#pragma unroll
    for (int kk = 0; kk < 2; ++kk) {
      int j = kk*4 + q4;                 // logical 16B chunk within row
      bf16x8 af[4], bfr[4];
#pragma unroll
      for (int mi=0; mi<4; ++mi){
        int row = wm + mi*16 + fm;
        af[mi] = *(const bf16x8*)&Als[row*GK + ((j ^ row) & 7)*8];
      }
#pragma unroll
      for (int ni=0; ni<4; ++ni){
        int row = wn + ni*16 + fm;
        bfr[ni] = *(const bf16x8*)&Bls[row*GK + ((j ^ row) & 7)*8];
      }
#pragma unroll
      for (int mi=0; mi<4; ++mi)
#pragma unroll
        for (int ni=0; ni<4; ++ni)
          acc[mi][ni] = __builtin_amdgcn_mfma_f32_16x16x32_bf16(af[mi], bfr[ni], acc[mi][ni], 0, 0, 0);
    }
    __syncthreads();
  }

  int seg = col0 >> 8;
  int colbase = col0 - seg*256;
  int cn = lane & 15, cr = (lane >> 4) * 4;
#pragma unroll
  for (int ni=0; ni<4; ++ni){
    int gcol = col0 + wn + ni*16 + cn;
    int col  = colbase + wn + ni*16 + cn;
    float bb = bias[gcol];
#pragma unroll
    for (int mi=0; mi<4; ++mi){
#pragma unroll
      for (int r=0; r<4; ++r){
        int row = row0 + wm + mi*16 + cr + r;
        if (row < M){
          float v = acc[mi][ni][r] + bb;
          if (seg == 0)      Cf [(size_t)row*256 + col] = v;
          else if (seg == 1) Cx1[(size_t)row*256 + col] = f2b(v);
          else               Cx2[(size_t)row*256 + col] = f2b(v);
        }
      }
    }
  }
}

// ---------------- CSR build by dst ----------------
__global__ void hist_kernel(const int* __restrict__ ei, int* __restrict__ deg){
  int e = blockIdx.x*blockDim.x + threadIdx.x;
  if (e < EE) atomicAdd(&deg[ei[EE + e]], 1);
}

// single-block full exclusive scan of deg -> rowptr, cursor (replaces scan1/2/3)
__global__ __launch_bounds__(1024) void scan_all_kernel(const int* __restrict__ deg,
                                                        int* __restrict__ rowptr,
                                                        int* __restrict__ cursor)
{
  __shared__ int wsums[16];
  int t = threadIdx.x, lane = t & 63, w = t >> 6;
  int carry = 0;
  for (int c = 0; c < (NN + 1023)/1024; ++c) {
    int i = c*1024 + t;
    int v = (i < NN) ? deg[i] : 0;
    int sc = v;
#pragma unroll
    for (int off = 1; off < 64; off <<= 1) {
      int o = __shfl_up(sc, off, 64);
      if (lane >= off) sc += o;
    }
    if (lane == 63) wsums[w] = sc;
    __syncthreads();
    if (w == 0) {
      int ws = (lane < 16) ? wsums[lane] : 0;
#pragma unroll
      for (int off = 1; off < 16; off <<= 1) {
        int o = __shfl_up(ws, off, 64);
        if (lane >= off) ws += o;
      }
      if (lane < 16) wsums[lane] = ws;
    }
    __syncthreads();
    int woff = (w > 0) ? wsums[w-1] : 0;
    int btot = wsums[15];
    if (i < NN) {
      int ex = carry + woff + sc - v;
      rowptr[i] = ex;
      cursor[i] = ex;
    }
    carry += btot;
    __syncthreads();   // wsums reused next chunk
  }
  if (t == 0) rowptr[NN] = carry;
}

// scatter: place edge into its dst bin. 8B per edge ({src, edge_id}).
__global__ void scatter_kernel(const int* __restrict__ ei,
                               int* __restrict__ cursor,
                               uint2* __restrict__ sedata){
  int e = blockIdx.x*blockDim.x + threadIdx.x;
  if (e >= EE) return;
  int s = ei[e];
  int d = ei[EE + e];
  int pos = atomicAdd(&cursor[d], 1);
  uint2 se; se.x = (unsigned)s; se.y = (unsigned)e;
  sedata[pos] = se;
}

// ---------------- per-node attention: batched 8-deep gather pipeline + packed fp32 ----------------
// (1 wave per node. Epilogue normalizes this node's alpha entries in place
//  — the wave owns all edges of v, so denom is complete; alpha_fin eliminated.)
#define LOAD8(Q, B0)                                               \
  if ((B0) < cnt) {                                                \
    _Pragma("unroll")                                              \
    for (int t = 0; t < 8; ++t) {                                  \
      int sj = rlane_i(s, ((B0) + t) & 63);                        \
      Q[t] = *(const uint2*)(xlp + ((size_t)sj << 8));             \
    }                                                              \
  }

#define PROC8(Q, B0)                                               \
  _Pragma("unroll")                                                \
  for (int t = 0; t < 8; ++t) {                                    \
    int j = (B0) + t;                                              \
    if (j < cnt) {                                                 \
      float ruj = rlane_f(edx, j);                                 \
      float rvj = rlane_f(edy, j);                                 \
      float dj  = rlane_f(edz, j);                                 \
      f32x2 x01 = unpk(Q[t].x), x23 = unpk(Q[t].y);                \
      f32x2 t01 = fma2(set2(ruj), we0a, xr01);                     \
      t01 = fma2(set2(rvj), we1a, t01);                            \
      t01 = fma2(set2(dj),  we2a, t01);                            \
      t01 = t01 + x01;                                             \
      f32x2 t23 = fma2(set2(ruj), we0b, xr23);                     \
      t23 = fma2(set2(rvj), we1b, t23);                            \
      t23 = fma2(set2(dj),  we2b, t23);                            \
      t23 = t23 + x23;                                             \
      t01 = max2(t01, t01*0.2f);                                   \
      t23 = max2(t23, t23*0.2f);                                   \
      f32x2 pd = t01*atta;                                         \
      pd = fma2(t23, attb, pd);                                    \
      float p = pd.x + pd.y;                                       \
      p += __shfl_xor(p, 1, 64);                                   \
      p += __shfl_xor(p, 2, 64);                                   \
      p += __shfl_xor(p, 4, 64);                                   \
      p += __shfl_xor(p, 8, 64);                                   \
      float exv = __expf(p);                                       \
      denom += exv;                                                \
      int ej = rlane_i(e, j);                                      \
      if ((lane & 15) == 0) alpha_out[(size_t)ej*4 + head] = exv;  \
      f32x2 ex2 = set2(exv);                                       \
      agg01 = fma2(ex2, x01, agg01);                               \
      agg23 = fma2(ex2, x23, agg23);                               \
    }                                                              \
  }

__global__ __launch_bounds__(128) void node_attn_kernel(
    const uint2* __restrict__ sedata, const float* __restrict__ nuv,
    const unsigned short* __restrict__ xl, const unsigned short* __restrict__ xr,
    const float* __restrict__ We, const float* __restrict__ att,
    const float* __restrict__ cbias, const float* __restrict__ gamma,
    const float* __restrict__ beta,
    const int* __restrict__ rowptr,
    const float* __restrict__ identity,
    float* __restrict__ alpha_out,
    unsigned short* __restrict__ hbuf)
{
  int wid  = threadIdx.x >> 6;
  int lane = threadIdx.x & 63;
  int v = blockIdx.x*2 + wid;
  if (v >= NN) return;
  int c0 = lane*4;
  int head = lane >> 4;

  f32x2 we0a, we0b, we1a, we1b, we2a, we2b, atta, attb;
  we0a.x = We[c0];       we0a.y = We[c0+1];       we0b.x = We[c0+2];       we0b.y = We[c0+3];
  we1a.x = We[256+c0];   we1a.y = We[256+c0+1];   we1b.x = We[256+c0+2];   we1b.y = We[256+c0+3];
  we2a.x = We[512+c0];   we2a.y = We[512+c0+1];   we2b.x = We[512+c0+2];   we2b.y = We[512+c0+3];
  atta.x = att[c0];      atta.y = att[c0+1];      attb.x = att[c0+2];      attb.y = att[c0+3];
  uint2 xrq = *(const uint2*)(xr + (size_t)v*256 + c0);
  f32x2 xr01 = unpk(xrq.x), xr23 = unpk(xrq.y);
  const unsigned short* xlp = xl + c0;
  float2 duv = *(const float2*)(nuv + 2*(size_t)v);

  int rs = rowptr[v], re = rowptr[v+1];
  int deg = re - rs;

  float denom = 0.f;
  f32x2 agg01 = set2(0.f), agg23 = set2(0.f);

  for (int base = 0; base < deg; base += 64) {
    int cnt = min(64, deg - base);
    int s = 0, e = 0;
    if (lane < cnt) {
      uint2 se = sedata[rs + base + lane];
      s = (int)se.x;
      e = (int)se.y;
    }
    // recompute geometry (bit-identical to old scatter-side math)
    float2 suv = *(const float2*)(nuv + 2*(size_t)s);
    float edx = duv.x - suv.x;
    float edy = duv.y - suv.y;
    float edz = sqrtf(edx*edx + edy*edy);

    uint2 qa[8], qb[8];
    LOAD8(qa, 0);
    for (int b0 = 0; b0 < cnt; b0 += 16) {
      LOAD8(qb, b0 + 8);
      PROC8(qa, b0);
      LOAD8(qa, b0 + 16);
      PROC8(qb, b0 + 8);
    }
  }

  // ---- in-place alpha normalization (replaces alpha_fin) ----
  // denom is uniform within each 16-lane head group.
  float dd0 = rlane_f(denom, 0)  + 1e-16f;
  float dd1 = rlane_f(denom, 16) + 1e-16f;
  float dd2 = rlane_f(denom, 32) + 1e-16f;
  float dd3 = rlane_f(denom, 48) + 1e-16f;
  // ensure this wave's exv stores are visible before re-reading
  asm volatile("s_waitcnt vmcnt(0)" ::: "memory");
  for (int j = lane; j < deg; j += 64) {
    unsigned e = sedata[rs + j].y;
    float4 a = *(float4*)(alpha_out + (size_t)e*4);
    a.x /= dd0; a.y /= dd1; a.z /= dd2; a.w /= dd3;   // same div op as old alpha_fin
    *(float4*)(alpha_out + (size_t)e*4) = a;
  }

  float rdenom = 1.0f / (denom + 1e-16f);

  float a0 = agg01.x*rdenom + cbias[c0];
  float a1 = agg01.y*rdenom + cbias[c0+1];
  float a2 = agg23.x*rdenom + cbias[c0+2];
  float a3 = agg23.y*rdenom + cbias[c0+3];

  float ps  = a0 + a1 + a2 + a3;
  float ps2 = a0*a0 + a1*a1 + a2*a2 + a3*a3;
#pragma unroll
  for (int off = 1; off < 64; off <<= 1) {
    ps  += __shfl_xor(ps,  off, 64);
    ps2 += __shfl_xor(ps2, off, 64);
  }
  float mu  = ps  * (1.0f/256.0f);
  float var = ps2 * (1.0f/256.0f) - mu*mu;
  float rstd = rsqrtf(var + 1e-5f);
  float4 g  = ld4(gamma + c0);
  float4 b  = ld4(beta  + c0);
  float4 idv = ld4(identity + (size_t)v*256 + c0);
  float y0 = (a0 - mu)*rstd*g.x + b.x;
  float y1 = (a1 - mu)*rstd*g.y + b.y;
  float y2 = (a2 - mu)*rstd*g.z + b.z;
  float y3 = (a3 - mu)*rstd*g.w + b.w;
  y0 = y0 / (1.0f + __expf(-y0)) + idv.x;
  y1 = y1 / (1.0f + __expf(-y1)) + idv.y;
  y2 = y2 / (1.0f + __expf(-y2)) + idv.z;
  y3 = y3 / (1.0f + __expf(-y3)) + idv.w;
  ushort4 hq; hq.x=f2b(y0); hq.y=f2b(y1); hq.z=f2b(y2); hq.w=f2b(y3);
  *(ushort4*)(hbuf + (size_t)v*256 + c0) = hq;
}

extern "C" void kernel_launch(void* const* d_in, const int* in_sizes, int n_in,
                              void* d_out, int out_size, void* d_ws, size_t ws_size,
                              hipStream_t stream)
{
  const float* x      = (const float*)d_in[0];
  const float* kpts   = (const float*)d_in[1];
  const float* pts3d  = (const float*)d_in[2];
  const int*   ei     = (const int*)d_in[3];
  const float* W1     = (const float*)d_in[4];
  const float* b1     = (const float*)d_in[5];
  const float* W2     = (const float*)d_in[6];
  const float* b2     = (const float*)d_in[7];
  const float* Wres   = (const float*)d_in[8];
  const float* bres   = (const float*)d_in[9];
  const float* Wl     = (const float*)d_in[10];
  const float* bl     = (const float*)d_in[11];
  const float* Wr     = (const float*)d_in[12];
  const float* br     = (const float*)d_in[13];
  const float* We     = (const float*)d_in[14];
  const float* att    = (const float*)d_in[15];
  const float* cbias  = (const float*)d_in[16];
  const float* gamma  = (const float*)d_in[17];
  const float* beta   = (const float*)d_in[18];
  const float* Wp     = (const float*)d_in[19];
  const float* bp     = (const float*)d_in[20];

  float* out       = (float*)d_out;
  float* alpha_out = out + (size_t)NN*HIDC;

  // workspace layout (units: float elements) — ~153 MB
  float* wsf = (float*)d_ws;
  float*          identity = wsf;                               // 12,800,000 f
  unsigned short* xl       = (unsigned short*)(wsf + 12800000); // 12,812,288 us
  unsigned short* xr       = (unsigned short*)(wsf + 19206144);
  unsigned short* nodex    = (unsigned short*)(wsf + 25612288); // 16,015,360 us
  unsigned short* hbuf     = (unsigned short*)(wsf + 25612288); // alias nodex (dead after gemm3)
  unsigned short* wt       = (unsigned short*)(wsf + 33619968); // 311,296 us
  float*          biascat  = wsf + 33775616;                    // 768 f
  uint2*          sedata   = (uint2*)(wsf + 33976384);          // 800,000 uint2 (1.6M f)
  float*          nuv      = wsf + 35576384;                    // 100,000 f (norm_uv)
  int*            deg      = (int*)(wsf + 37976384);            // 50,000 i
  int*            rowptr   = (int*)(wsf + 38026384);            // 50,001 i
  int*            cursor   = (int*)(wsf + 38076385);            // 50,000 i

  unsigned short* wtcat = wt;            // 768 x 320 (Wres_T | Wl_T | Wr_T)
  unsigned short* wtp   = wt + 245760;   // 256 x 256

  // 1) fused prep (cvt_x + node_mlp/nuv/deg0 + cvt_w)
  prep_kernel<<<PREP_CVTX + PREP_MLP + PREP_CVTW, 256, 0, stream>>>(
      x, nodex, kpts, pts3d, W1, b1, W2, b2, nuv, deg,
      Wres, Wl, Wr, Wp, bres, bl, br, wt, biascat);

  // 2) fused triple GEMM: [identity | x_l | x_r] = nodex @ [Wres|Wl|Wr] + bias
  dim3 g3(6, NPAD/128);
  mfma_gemm_kernel<<<g3, 256, 0, stream>>>(nodex, wtcat, biascat, identity, xl, xr, NN, INCH);

  // 3) degree histogram
  hist_kernel<<<(EE+255)/256, 256, 0, stream>>>(ei, deg);

  // 4) single-launch full scan -> rowptr, cursor
  scan_all_kernel<<<1, 1024, 0, stream>>>(deg, rowptr, cursor);

  // 5) CSR scatter
  scatter_kernel<<<(EE+255)/256, 256, 0, stream>>>(ei, cursor, sedata);

  // 6) attention + layernorm + silu + residual + in-place alpha normalize
  node_attn_kernel<<<(NN+1)/2, 128, 0, stream>>>(sedata, nuv, xl, xr, We, att,
                                                 cbias, gamma, beta,
                                                 rowptr, identity,
                                                 alpha_out, hbuf);

  // 7) output projection
  dim3 g1(2, NPAD/128);
  mfma_gemm_kernel<<<g1, 256, 0, stream>>>(hbuf, wtp, bp, out, nullptr, nullptr, NN, HIDC);
}

// Round 8
// 583.009 us; speedup vs baseline: 1.0001x; 1.0001x over previous
//
#include <hip/hip_runtime.h>
#include <math.h>

#define NN 50000
#define NPAD 50048
#define EE 800000
#define HIDC 256
#define INCH 320

typedef __attribute__((ext_vector_type(8))) short bf16x8;
typedef __attribute__((ext_vector_type(4))) float f32x4;
typedef __attribute__((ext_vector_type(2))) float f32x2;

static __device__ __forceinline__ float4 ld4(const float* p){ return *(const float4*)p; }

static __device__ __forceinline__ unsigned short f2b(float f){
  union { float f; unsigned u; } v; v.f = f;
  unsigned r = v.u + 0x7fffu + ((v.u >> 16) & 1u);
  return (unsigned short)(r >> 16);
}
static __device__ __forceinline__ float b2f(unsigned short u){
  union { unsigned u; float f; } v; v.u = ((unsigned)u) << 16; return v.f;
}
static __device__ __forceinline__ float rlane_f(float v, int l){
  return __uint_as_float(__builtin_amdgcn_readlane(__float_as_uint(v), l));
}
static __device__ __forceinline__ int rlane_i(int v, int l){
  return __builtin_amdgcn_readlane(v, l);
}
// unpack two bf16 packed in a u32 -> 2 floats (lo = .x, hi = .y)
static __device__ __forceinline__ f32x2 unpk(unsigned u){
  f32x2 r;
  r.x = __uint_as_float(u << 16);
  r.y = __uint_as_float(u & 0xffff0000u);
  return r;
}
static __device__ __forceinline__ f32x2 fma2(f32x2 a, f32x2 b, f32x2 c){
  return __builtin_elementwise_fma(a, b, c);
}
static __device__ __forceinline__ f32x2 max2(f32x2 a, f32x2 b){
  return __builtin_elementwise_max(a, b);
}
static __device__ __forceinline__ f32x2 set2(float v){ f32x2 r; r.x = v; r.y = v; return r; }

typedef const __attribute__((address_space(1))) unsigned int* gas_u32;
typedef __attribute__((address_space(3))) unsigned int* las_u32;
static __device__ __forceinline__ void gload_lds16(const void* g, void* l){
  __builtin_amdgcn_global_load_lds((gas_u32)g, (las_u32)l, 16, 0, 0);
}

// ---------------- convert x (fp32 50000x256) into node_x bf16 (NPAD x 320, cols 0..255) ----------------
__global__ void cvt_x_kernel(const float* __restrict__ x, unsigned short* __restrict__ nodex)
{
  int t = blockIdx.x*blockDim.x + threadIdx.x;
  int row = t >> 6;
  if (row >= NN) return;
  int c4 = (t & 63) * 4;
  float4 v = ld4(x + (size_t)row*256 + c4);
  ushort4 o;
  o.x = f2b(v.x); o.y = f2b(v.y); o.z = f2b(v.z); o.w = f2b(v.w);
  *(ushort4*)(nodex + (size_t)row*320 + c4) = o;
}

// ---------------- node positional MLP: writes bf16 into node_x cols 256..319 + norm_uv table ----------------
__global__ void node_mlp_kernel(const float* __restrict__ kpts,
                                const float* __restrict__ pts3d,
                                const float* __restrict__ W1, const float* __restrict__ b1,
                                const float* __restrict__ W2, const float* __restrict__ b2,
                                unsigned short* __restrict__ nodex,
                                float* __restrict__ nuv)
{
  int i = blockIdx.x*blockDim.x + threadIdx.x;
  if (i >= NN) return;
  float u = kpts[2*i]   * (1.0f/1216.0f);
  float v = kpts[2*i+1] * (1.0f/352.0f);
  float d = pts3d[3*i+2];
  float2 uv; uv.x = u; uv.y = v;
  *(float2*)(nuv + 2*i) = uv;
  float h[32];
#pragma unroll
  for (int j=0;j<32;++j){
    float t = u*W1[j] + v*W1[32+j] + d*W1[64+j] + b1[j];
    h[j] = t / (1.0f + __expf(-t));   // silu
  }
  for (int o=0;o<64;o+=4){
    float s0=b2[o], s1=b2[o+1], s2=b2[o+2], s3=b2[o+3];
#pragma unroll
    for (int j=0;j<32;++j){
      float hj = h[j];
      const float* w = W2 + j*64 + o;
      s0 += hj*w[0]; s1 += hj*w[1]; s2 += hj*w[2]; s3 += hj*w[3];
    }
    ushort4 r; r.x=f2b(s0); r.y=f2b(s1); r.z=f2b(s2); r.w=f2b(s3);
    *(ushort4*)(nodex + (size_t)i*320 + 256 + o) = r;
  }
}

// ---------------- convert + transpose weights to bf16 N-major (K contiguous) + bias concat ----------------
__global__ void cvt_w_kernel(const float* __restrict__ Wres, const float* __restrict__ Wl,
                             const float* __restrict__ Wr,   const float* __restrict__ Wp,
                             const float* __restrict__ bres, const float* __restrict__ bl,
                             const float* __restrict__ br,
                             unsigned short* __restrict__ wt, float* __restrict__ biascat)
{
  int t = blockIdx.x*blockDim.x + threadIdx.x;   // 312064 threads
  if (t < 245760) {
    int which = t / 81920;
    int rem = t % 81920;
    int n = rem / 320, k = rem % 320;
    const float* W = (which == 0) ? Wres : (which == 1) ? Wl : Wr;
    wt[(size_t)which*81920 + rem] = f2b(W[(size_t)k*256 + n]);
  } else if (t < 311296) {
    int r = t - 245760;
    int n = r / 256, k = r % 256;
    wt[245760 + r] = f2b(Wp[(size_t)k*256 + n]);
  } else {
    int r = t - 311296;   // 0..767
    const float* src = (r < 256) ? bres : (r < 512) ? bl : br;
    biascat[r] = src[r & 255];
  }
}

// ---------------- bf16 MFMA GEMM: C(M,Nt) = A(M,K) @ BT(Nt,K)^T + bias ----------------
// GK=64 + XOR slot-swizzle; grid transposed (col-blocks fastest).
#define GK 64
__global__ __launch_bounds__(256) void mfma_gemm_kernel(
    const unsigned short* __restrict__ A,
    const unsigned short* __restrict__ BT,
    const float* __restrict__ bias,
    float* __restrict__ Cf,
    unsigned short* __restrict__ Cx1,
    unsigned short* __restrict__ Cx2,
    int M, int K)
{
  __shared__ unsigned short Als[128*GK];   // 16 KB
  __shared__ unsigned short Bls[128*GK];   // 16 KB
  int tid = threadIdx.x;
  int lane = tid & 63, wave = tid >> 6;
  int wm = (wave >> 1) * 64, wn = (wave & 1) * 64;
  int row0 = blockIdx.y * 128, col0 = blockIdx.x * 128;

  f32x4 acc[4][4];
#pragma unroll
  for (int i=0;i<4;++i)
#pragma unroll
    for (int j=0;j<4;++j){ acc[i][j].x=0.f; acc[i][j].y=0.f; acc[i][j].z=0.f; acc[i][j].w=0.f; }

  int fm = lane & 15;
  int q4 = lane >> 4;          // quarter-wave index 0..3

  for (int k0 = 0; k0 < K; k0 += GK) {
#pragma unroll
    for (int it = 0; it < 4; ++it) {
      int cgl = it*256 + tid;            // chunk id 0..1023 (16B chunks)
      int r = cgl >> 3;                  // tile row 0..127
      int kb = ((cgl ^ r) & 7) * 8;      // swizzled k-chunk (elements)
      gload_lds16(A  + (size_t)(row0 + r)*K + k0 + kb, Als + (it*256 + wave*64)*8);
      gload_lds16(BT + (size_t)(col0 + r)*K + k0 + kb, Bls + (it*256 + wave*64)*8);
    }
    __syncthreads();

#pragma unroll
    for (int kk = 0; kk < 2; ++kk) {
      int j = kk*4 + q4;                 // logical 16B chunk within row
      bf16x8 af[4], bfr[4];
#pragma unroll
      for (int mi=0; mi<4; ++mi){
        int row = wm + mi*16 + fm;
        af[mi] = *(const bf16x8*)&Als[row*GK + ((j ^ row) & 7)*8];
      }
#pragma unroll
      for (int ni=0; ni<4; ++ni){
        int row = wn + ni*16 + fm;
        bfr[ni] = *(const bf16x8*)&Bls[row*GK + ((j ^ row) & 7)*8];
      }
#pragma unroll
      for (int mi=0; mi<4; ++mi)
#pragma unroll
        for (int ni=0; ni<4; ++ni)
          acc[mi][ni] = __builtin_amdgcn_mfma_f32_16x16x32_bf16(af[mi], bfr[ni], acc[mi][ni], 0, 0, 0);
    }
    __syncthreads();
  }

  int seg = col0 >> 8;
  int colbase = col0 - seg*256;
  int cn = lane & 15, cr = (lane >> 4) * 4;
#pragma unroll
  for (int ni=0; ni<4; ++ni){
    int gcol = col0 + wn + ni*16 + cn;
    int col  = colbase + wn + ni*16 + cn;
    float bb = bias[gcol];
#pragma unroll
    for (int mi=0; mi<4; ++mi){
#pragma unroll
      for (int r=0; r<4; ++r){
        int row = row0 + wm + mi*16 + cr + r;
        if (row < M){
          float v = acc[mi][ni][r] + bb;
          if (seg == 0)      Cf [(size_t)row*256 + col] = v;
          else if (seg == 1) Cx1[(size_t)row*256 + col] = f2b(v);
          else               Cx2[(size_t)row*256 + col] = f2b(v);
        }
      }
    }
  }
}

// ---------------- CSR build by dst ----------------
__global__ void hist_kernel(const int* __restrict__ ei, int* __restrict__ deg){
  int e = blockIdx.x*blockDim.x + threadIdx.x;
  if (e < EE) atomicAdd(&deg[ei[EE + e]], 1);
}

// parallel 3-phase scan
__global__ __launch_bounds__(1024) void scan1_kernel(const int* __restrict__ deg,
                                                     int* __restrict__ incl, int* __restrict__ bsum){
  __shared__ int wsums[16];
  int t = threadIdx.x, lane = t & 63, w = t >> 6;
  int i = blockIdx.x*1024 + t;
  int v = (i < NN) ? deg[i] : 0;
  int sc = v;
#pragma unroll
  for (int off = 1; off < 64; off <<= 1) {
    int o = __shfl_up(sc, off, 64);
    if (lane >= off) sc += o;
  }
  if (lane == 63) wsums[w] = sc;
  __syncthreads();
  if (w == 0) {
    int ws = (lane < 16) ? wsums[lane] : 0;
#pragma unroll
    for (int off = 1; off < 16; off <<= 1) {
      int o = __shfl_up(ws, off, 64);
      if (lane >= off) ws += o;
    }
    if (lane < 16) wsums[lane] = ws;
  }
  __syncthreads();
  int woff = (w > 0) ? wsums[w-1] : 0;
  if (i < NN) incl[i] = sc + woff;
  if (t == 1023) bsum[blockIdx.x] = woff + sc;
}

__global__ void scan2_kernel(int* __restrict__ bsum, int nblk){
  int lane = threadIdx.x;
  int v = (lane < nblk) ? bsum[lane] : 0;
#pragma unroll
  for (int off = 1; off < 64; off <<= 1) {
    int o = __shfl_up(v, off, 64);
    if (lane >= off) v += o;
  }
  if (lane < nblk) bsum[lane] = v;
}

__global__ __launch_bounds__(1024) void scan3_kernel(const int* __restrict__ incl,
                                                     const int* __restrict__ deg,
                                                     const int* __restrict__ bsum,
                                                     int* __restrict__ rowptr, int* __restrict__ cursor,
                                                     int nblk){
  int i = blockIdx.x*1024 + threadIdx.x;
  if (i < NN) {
    int b = blockIdx.x;
    int prev = (b > 0) ? bsum[b-1] : 0;
    int ex = prev + incl[i] - deg[i];
    rowptr[i] = ex;
    cursor[i] = ex;
  }
  if (i == 0) rowptr[NN] = bsum[nblk-1];
}

// scatter: place edge into its dst bin. 8B per edge ({src, edge_id}).
__global__ void scatter_kernel(const int* __restrict__ ei,
                               int* __restrict__ cursor,
                               uint2* __restrict__ sedata){
  int e = blockIdx.x*blockDim.x + threadIdx.x;
  if (e >= EE) return;
  int s = ei[e];
  int d = ei[EE + e];
  int pos = atomicAdd(&cursor[d], 1);
  uint2 se; se.x = (unsigned)s; se.y = (unsigned)e;
  sedata[pos] = se;
}

// ---------------- per-node attention: batched 8-deep gather pipeline + packed fp32 ----------------
// (1 wave per node, 64 lanes x 4 channels, readlane-broadcast edge scalars,
//  8-deep flat gather pipeline. Geometry recomputed from norm_uv (L2-resident).
//  vbase: node offset — kernel is dispatched in 4 quarters so that sub-attn
//  kernels surface in the rocprof top-5 window (diagnostic, zero-cost split).)
#define LOAD8(Q, B0)                                               \
  if ((B0) < cnt) {                                                \
    _Pragma("unroll")                                              \
    for (int t = 0; t < 8; ++t) {                                  \
      int sj = rlane_i(s, ((B0) + t) & 63);                        \
      Q[t] = *(const uint2*)(xlp + ((size_t)sj << 8));             \
    }                                                              \
  }

#define PROC8(Q, B0)                                               \
  _Pragma("unroll")                                                \
  for (int t = 0; t < 8; ++t) {                                    \
    int j = (B0) + t;                                              \
    if (j < cnt) {                                                 \
      float ruj = rlane_f(edx, j);                                 \
      float rvj = rlane_f(edy, j);                                 \
      float dj  = rlane_f(edz, j);                                 \
      f32x2 x01 = unpk(Q[t].x), x23 = unpk(Q[t].y);                \
      f32x2 t01 = fma2(set2(ruj), we0a, xr01);                     \
      t01 = fma2(set2(rvj), we1a, t01);                            \
      t01 = fma2(set2(dj),  we2a, t01);                            \
      t01 = t01 + x01;                                             \
      f32x2 t23 = fma2(set2(ruj), we0b, xr23);                     \
      t23 = fma2(set2(rvj), we1b, t23);                            \
      t23 = fma2(set2(dj),  we2b, t23);                            \
      t23 = t23 + x23;                                             \
      t01 = max2(t01, t01*0.2f);                                   \
      t23 = max2(t23, t23*0.2f);                                   \
      f32x2 pd = t01*atta;                                         \
      pd = fma2(t23, attb, pd);                                    \
      float p = pd.x + pd.y;                                       \
      p += __shfl_xor(p, 1, 64);                                   \
      p += __shfl_xor(p, 2, 64);                                   \
      p += __shfl_xor(p, 4, 64);                                   \
      p += __shfl_xor(p, 8, 64);                                   \
      float exv = __expf(p);                                       \
      denom += exv;                                                \
      int ej = rlane_i(e, j);                                      \
      if ((lane & 15) == 0) alpha_out[(size_t)ej*4 + head] = exv;  \
      f32x2 ex2 = set2(exv);                                       \
      agg01 = fma2(ex2, x01, agg01);                               \
      agg23 = fma2(ex2, x23, agg23);                               \
    }                                                              \
  }

__global__ __launch_bounds__(128) void node_attn_kernel(
    const uint2* __restrict__ sedata, const float* __restrict__ nuv,
    const unsigned short* __restrict__ xl, const unsigned short* __restrict__ xr,
    const float* __restrict__ We, const float* __restrict__ att,
    const float* __restrict__ cbias, const float* __restrict__ gamma,
    const float* __restrict__ beta,
    const int* __restrict__ rowptr,
    const float* __restrict__ identity,
    float* __restrict__ alpha_out, float* __restrict__ denom_buf,
    unsigned short* __restrict__ hbuf,
    int vbase)
{
  int wid  = threadIdx.x >> 6;
  int lane = threadIdx.x & 63;
  int v = vbase + blockIdx.x*2 + wid;
  if (v >= NN) return;
  int c0 = lane*4;
  int head = lane >> 4;

  f32x2 we0a, we0b, we1a, we1b, we2a, we2b, atta, attb;
  we0a.x = We[c0];       we0a.y = We[c0+1];       we0b.x = We[c0+2];       we0b.y = We[c0+3];
  we1a.x = We[256+c0];   we1a.y = We[256+c0+1];   we1b.x = We[256+c0+2];   we1b.y = We[256+c0+3];
  we2a.x = We[512+c0];   we2a.y = We[512+c0+1];   we2b.x = We[512+c0+2];   we2b.y = We[512+c0+3];
  atta.x = att[c0];      atta.y = att[c0+1];      attb.x = att[c0+2];      attb.y = att[c0+3];
  uint2 xrq = *(const uint2*)(xr + (size_t)v*256 + c0);
  f32x2 xr01 = unpk(xrq.x), xr23 = unpk(xrq.y);
  const unsigned short* xlp = xl + c0;
  float2 duv = *(const float2*)(nuv + 2*(size_t)v);

  int rs = rowptr[v], re = rowptr[v+1];
  int deg = re - rs;

  float denom = 0.f;
  f32x2 agg01 = set2(0.f), agg23 = set2(0.f);

  for (int base = 0; base < deg; base += 64) {
    int cnt = min(64, deg - base);
    int s = 0, e = 0;
    if (lane < cnt) {
      uint2 se = sedata[rs + base + lane];
      s = (int)se.x;
      e = (int)se.y;
    }
    // recompute geometry (bit-identical to old scatter-side math)
    float2 suv = *(const float2*)(nuv + 2*(size_t)s);
    float edx = duv.x - suv.x;
    float edy = duv.y - suv.y;
    float edz = sqrtf(edx*edx + edy*edy);

    uint2 qa[8], qb[8];
    LOAD8(qa, 0);
    for (int b0 = 0; b0 < cnt; b0 += 16) {
      LOAD8(qb, b0 + 8);
      PROC8(qa, b0);
      LOAD8(qa, b0 + 16);
      PROC8(qb, b0 + 8);
    }
  }

  float rdenom = 1.0f / (denom + 1e-16f);
  if ((lane & 15) == 0) denom_buf[(size_t)v*4 + head] = denom;

  float a0 = agg01.x*rdenom + cbias[c0];
  float a1 = agg01.y*rdenom + cbias[c0+1];
  float a2 = agg23.x*rdenom + cbias[c0+2];
  float a3 = agg23.y*rdenom + cbias[c0+3];

  float ps  = a0 + a1 + a2 + a3;
  float ps2 = a0*a0 + a1*a1 + a2*a2 + a3*a3;
#pragma unroll
  for (int off = 1; off < 64; off <<= 1) {
    ps  += __shfl_xor(ps,  off, 64);
    ps2 += __shfl_xor(ps2, off, 64);
  }
  float mu  = ps  * (1.0f/256.0f);
  float var = ps2 * (1.0f/256.0f) - mu*mu;
  float rstd = rsqrtf(var + 1e-5f);
  float4 g  = ld4(gamma + c0);
  float4 b  = ld4(beta  + c0);
  float4 idv = ld4(identity + (size_t)v*256 + c0);
  float y0 = (a0 - mu)*rstd*g.x + b.x;
  float y1 = (a1 - mu)*rstd*g.y + b.y;
  float y2 = (a2 - mu)*rstd*g.z + b.z;
  float y3 = (a3 - mu)*rstd*g.w + b.w;
  y0 = y0 / (1.0f + __expf(-y0)) + idv.x;
  y1 = y1 / (1.0f + __expf(-y1)) + idv.y;
  y2 = y2 / (1.0f + __expf(-y2)) + idv.z;
  y3 = y3 / (1.0f + __expf(-y3)) + idv.w;
  ushort4 hq; hq.x=f2b(y0); hq.y=f2b(y1); hq.z=f2b(y2); hq.w=f2b(y3);
  *(ushort4*)(hbuf + (size_t)v*256 + c0) = hq;
}

// ---------------- finalize alpha: alpha[e,h] = ex[e,h] / (denom[dst,h]+1e-16) ----------------
__global__ void alpha_fin_kernel(const int* __restrict__ ei, const float* __restrict__ denom_buf,
                                 float* __restrict__ alpha)
{
  int e = blockIdx.x*blockDim.x + threadIdx.x;
  if (e >= EE) return;
  int d = ei[EE + e];
  float4 dn = ld4(denom_buf + (size_t)d*4);
  float4 a = ld4(alpha + (size_t)e*4);
  a.x /= (dn.x + 1e-16f);
  a.y /= (dn.y + 1e-16f);
  a.z /= (dn.z + 1e-16f);
  a.w /= (dn.w + 1e-16f);
  *(float4*)(alpha + (size_t)e*4) = a;
}

extern "C" void kernel_launch(void* const* d_in, const int* in_sizes, int n_in,
                              void* d_out, int out_size, void* d_ws, size_t ws_size,
                              hipStream_t stream)
{
  const float* x      = (const float*)d_in[0];
  const float* kpts   = (const float*)d_in[1];
  const float* pts3d  = (const float*)d_in[2];
  const int*   ei     = (const int*)d_in[3];
  const float* W1     = (const float*)d_in[4];
  const float* b1     = (const float*)d_in[5];
  const float* W2     = (const float*)d_in[6];
  const float* b2     = (const float*)d_in[7];
  const float* Wres   = (const float*)d_in[8];
  const float* bres   = (const float*)d_in[9];
  const float* Wl     = (const float*)d_in[10];
  const float* bl     = (const float*)d_in[11];
  const float* Wr     = (const float*)d_in[12];
  const float* br     = (const float*)d_in[13];
  const float* We     = (const float*)d_in[14];
  const float* att    = (const float*)d_in[15];
  const float* cbias  = (const float*)d_in[16];
  const float* gamma  = (const float*)d_in[17];
  const float* beta   = (const float*)d_in[18];
  const float* Wp     = (const float*)d_in[19];
  const float* bp     = (const float*)d_in[20];

  float* out       = (float*)d_out;
  float* alpha_out = out + (size_t)NN*HIDC;

  // workspace layout (units: float elements) — ~153 MB
  float* wsf = (float*)d_ws;
  float*          identity = wsf;                               // 12,800,000 f
  unsigned short* xl       = (unsigned short*)(wsf + 12800000); // 12,812,288 us
  unsigned short* xr       = (unsigned short*)(wsf + 19206144);
  unsigned short* nodex    = (unsigned short*)(wsf + 25612288); // 16,015,360 us
  unsigned short* hbuf     = (unsigned short*)(wsf + 25612288); // alias nodex (dead after gemm3)
  unsigned short* wt       = (unsigned short*)(wsf + 33619968); // 311,296 us
  float*          biascat  = wsf + 33775616;                    // 768 f
  float*          denomb   = wsf + 33776384;                    // 200,000 f
  uint2*          sedata   = (uint2*)(wsf + 33976384);          // 800,000 uint2 (1.6M f)
  float*          nuv      = wsf + 35576384;                    // 100,000 f (norm_uv)
  int*            incl     = (int*)(wsf + 37176384);            // 800,000 i scratch
  int*            deg      = (int*)(wsf + 37976384);            // 50,000 i
  int*            rowptr   = (int*)(wsf + 38026384);            // 50,001 i
  int*            cursor   = (int*)(wsf + 38076385);            // 50,000 i
  int*            bsum     = (int*)(wsf + 38126385);            // 64 i

  unsigned short* wtcat = wt;            // 768 x 320 (Wres_T | Wl_T | Wr_T)
  unsigned short* wtp   = wt + 245760;   // 256 x 256

  cvt_x_kernel<<<12500, 256, 0, stream>>>(x, nodex);
  node_mlp_kernel<<<(NN+255)/256, 256, 0, stream>>>(kpts, pts3d, W1, b1, W2, b2, nodex, nuv);
  cvt_w_kernel<<<1219, 256, 0, stream>>>(Wres, Wl, Wr, Wp, bres, bl, br, wt, biascat);

  // fused triple GEMM: [identity | x_l | x_r] = nodex @ [Wres|Wl|Wr] + bias
  // grid transposed: col-blocks fastest (share the A panel -> L2-resident)
  dim3 g3(6, NPAD/128);
  mfma_gemm_kernel<<<g3, 256, 0, stream>>>(nodex, wtcat, biascat, identity, xl, xr, NN, INCH);

  hipMemsetAsync(deg, 0, NN*sizeof(int), stream);
  hist_kernel<<<(EE+255)/256, 256, 0, stream>>>(ei, deg);
  int nblk = (NN + 1023) / 1024;   // 49
  scan1_kernel<<<nblk, 1024, 0, stream>>>(deg, incl, bsum);
  scan2_kernel<<<1, 64, 0, stream>>>(bsum, nblk);
  scan3_kernel<<<nblk, 1024, 0, stream>>>(incl, deg, bsum, rowptr, cursor, nblk);
  scatter_kernel<<<(EE+255)/256, 256, 0, stream>>>(ei, cursor, sedata);

  // attention in 4 quarter-dispatches (12500 nodes each) — zero-cost split so
  // sub-attn kernels become visible in the rocprof top-5 window.
  for (int q = 0; q < 4; ++q) {
    node_attn_kernel<<<6250, 128, 0, stream>>>(sedata, nuv, xl, xr, We, att,
                                               cbias, gamma, beta,
                                               rowptr, identity,
                                               alpha_out, denomb, hbuf,
                                               q * 12500);
  }
  alpha_fin_kernel<<<(EE+255)/256, 256, 0, stream>>>(ei, denomb, alpha_out);

  dim3 g1(2, NPAD/128);
  mfma_gemm_kernel<<<g1, 256, 0, stream>>>(hbuf, wtp, bp, out, nullptr, nullptr, NN, HIDC);
}

// Round 9
// 556.446 us; speedup vs baseline: 1.0479x; 1.0477x over previous
//
#include <hip/hip_runtime.h>
#include <math.h>

#define NN 50000
#define NPAD 50048
#define EE 800000
#define HIDC 256
#define INCH 320

typedef __attribute__((ext_vector_type(8))) short bf16x8;
typedef __attribute__((ext_vector_type(4))) float f32x4;
typedef __attribute__((ext_vector_type(2))) float f32x2;

static __device__ __forceinline__ float4 ld4(const float* p){ return *(const float4*)p; }

static __device__ __forceinline__ unsigned short f2b(float f){
  union { float f; unsigned u; } v; v.f = f;
  unsigned r = v.u + 0x7fffu + ((v.u >> 16) & 1u);
  return (unsigned short)(r >> 16);
}
static __device__ __forceinline__ float b2f(unsigned short u){
  union { unsigned u; float f; } v; v.u = ((unsigned)u) << 16; return v.f;
}
static __device__ __forceinline__ float rlane_f(float v, int l){
  return __uint_as_float(__builtin_amdgcn_readlane(__float_as_uint(v), l));
}
static __device__ __forceinline__ int rlane_i(int v, int l){
  return __builtin_amdgcn_readlane(v, l);
}
// unpack two bf16 packed in a u32 -> 2 floats (lo = .x, hi = .y)
static __device__ __forceinline__ f32x2 unpk(unsigned u){
  f32x2 r;
  r.x = __uint_as_float(u << 16);
  r.y = __uint_as_float(u & 0xffff0000u);
  return r;
}
static __device__ __forceinline__ f32x2 fma2(f32x2 a, f32x2 b, f32x2 c){
  return __builtin_elementwise_fma(a, b, c);
}
static __device__ __forceinline__ f32x2 max2(f32x2 a, f32x2 b){
  return __builtin_elementwise_max(a, b);
}
static __device__ __forceinline__ f32x2 set2(float v){ f32x2 r; r.x = v; r.y = v; return r; }

typedef const __attribute__((address_space(1))) unsigned int* gas_u32;
typedef __attribute__((address_space(3))) unsigned int* las_u32;
static __device__ __forceinline__ void gload_lds16(const void* g, void* l){
  __builtin_amdgcn_global_load_lds((gas_u32)g, (las_u32)l, 16, 0, 0);
}

// ---------------- convert x (fp32 50000x256) into node_x bf16 (NPAD x 320, cols 0..255) ----------------
__global__ void cvt_x_kernel(const float* __restrict__ x, unsigned short* __restrict__ nodex)
{
  int t = blockIdx.x*blockDim.x + threadIdx.x;
  int row = t >> 6;
  if (row >= NN) return;
  int c4 = (t & 63) * 4;
  float4 v = ld4(x + (size_t)row*256 + c4);
  ushort4 o;
  o.x = f2b(v.x); o.y = f2b(v.y); o.z = f2b(v.z); o.w = f2b(v.w);
  *(ushort4*)(nodex + (size_t)row*320 + c4) = o;
}

// ---------------- node positional MLP: writes bf16 into node_x cols 256..319 + norm_uv table ----------------
__global__ void node_mlp_kernel(const float* __restrict__ kpts,
                                const float* __restrict__ pts3d,
                                const float* __restrict__ W1, const float* __restrict__ b1,
                                const float* __restrict__ W2, const float* __restrict__ b2,
                                unsigned short* __restrict__ nodex,
                                float* __restrict__ nuv)
{
  int i = blockIdx.x*blockDim.x + threadIdx.x;
  if (i >= NN) return;
  float u = kpts[2*i]   * (1.0f/1216.0f);
  float v = kpts[2*i+1] * (1.0f/352.0f);
  float d = pts3d[3*i+2];
  float2 uv; uv.x = u; uv.y = v;
  *(float2*)(nuv + 2*i) = uv;
  float h[32];
#pragma unroll
  for (int j=0;j<32;++j){
    float t = u*W1[j] + v*W1[32+j] + d*W1[64+j] + b1[j];
    h[j] = t / (1.0f + __expf(-t));   // silu
  }
  for (int o=0;o<64;o+=4){
    float s0=b2[o], s1=b2[o+1], s2=b2[o+2], s3=b2[o+3];
#pragma unroll
    for (int j=0;j<32;++j){
      float hj = h[j];
      const float* w = W2 + j*64 + o;
      s0 += hj*w[0]; s1 += hj*w[1]; s2 += hj*w[2]; s3 += hj*w[3];
    }
    ushort4 r; r.x=f2b(s0); r.y=f2b(s1); r.z=f2b(s2); r.w=f2b(s3);
    *(ushort4*)(nodex + (size_t)i*320 + 256 + o) = r;
  }
}

// ---------------- convert + transpose weights to bf16 N-major (K contiguous) + bias concat ----------------
__global__ void cvt_w_kernel(const float* __restrict__ Wres, const float* __restrict__ Wl,
                             const float* __restrict__ Wr,   const float* __restrict__ Wp,
                             const float* __restrict__ bres, const float* __restrict__ bl,
                             const float* __restrict__ br,
                             unsigned short* __restrict__ wt, float* __restrict__ biascat)
{
  int t = blockIdx.x*blockDim.x + threadIdx.x;   // 312064 threads
  if (t < 245760) {
    int which = t / 81920;
    int rem = t % 81920;
    int n = rem / 320, k = rem % 320;
    const float* W = (which == 0) ? Wres : (which == 1) ? Wl : Wr;
    wt[(size_t)which*81920 + rem] = f2b(W[(size_t)k*256 + n]);
  } else if (t < 311296) {
    int r = t - 245760;
    int n = r / 256, k = r % 256;
    wt[245760 + r] = f2b(Wp[(size_t)k*256 + n]);
  } else {
    int r = t - 311296;   // 0..767
    const float* src = (r < 256) ? bres : (r < 512) ? bl : br;
    biascat[r] = src[r & 255];
  }
}

// ---------------- bf16 MFMA GEMM: C(M,Nt) = A(M,K) @ BT(Nt,K)^T + bias ----------------
// 128x256 tile (per-wave 64x128, acc[4][8]): r8 counters showed the 128x128
// version sync-bound (MfmaUtil 10.8%, occ 26%, HBM 33%) — widening N doubles
// MFMA per barrier, halves block count, and cuts A re-reads 6->3 (g3) / ->1 (g1).
// GK=64 + XOR slot-swizzle; per-element K-accumulation order unchanged.
#define GK 64
__global__ __launch_bounds__(256, 2) void mfma_gemm_kernel(
    const unsigned short* __restrict__ A,
    const unsigned short* __restrict__ BT,
    const float* __restrict__ bias,
    float* __restrict__ Cf,
    unsigned short* __restrict__ Cx1,
    unsigned short* __restrict__ Cx2,
    int M, int K)
{
  __shared__ unsigned short Als[128*GK];   // 16 KB
  __shared__ unsigned short Bls[256*GK];   // 32 KB
  int tid = threadIdx.x;
  int lane = tid & 63, wave = tid >> 6;
  int wm = (wave >> 1) * 64;          // 0 / 64
  int wn = (wave & 1) * 128;          // 0 / 128
  int row0 = blockIdx.y * 128, col0 = blockIdx.x * 256;

  f32x4 acc[4][8];
#pragma unroll
  for (int i=0;i<4;++i)
#pragma unroll
    for (int j=0;j<8;++j){ acc[i][j].x=0.f; acc[i][j].y=0.f; acc[i][j].z=0.f; acc[i][j].w=0.f; }

  int fm = lane & 15;
  int q4 = lane >> 4;          // quarter-wave index 0..3

  for (int k0 = 0; k0 < K; k0 += GK) {
#pragma unroll
    for (int it = 0; it < 4; ++it) {     // A: 128 rows x 64 cols = 1024 x 16B chunks
      int cgl = it*256 + tid;
      int r = cgl >> 3;
      int kb = ((cgl ^ r) & 7) * 8;      // swizzled k-chunk (elements)
      gload_lds16(A  + (size_t)(row0 + r)*K + k0 + kb, Als + (it*256 + wave*64)*8);
    }
#pragma unroll
    for (int it = 0; it < 8; ++it) {     // B: 256 rows x 64 cols = 2048 x 16B chunks
      int cgl = it*256 + tid;
      int r = cgl >> 3;
      int kb = ((cgl ^ r) & 7) * 8;
      gload_lds16(BT + (size_t)(col0 + r)*K + k0 + kb, Bls + (it*256 + wave*64)*8);
    }
    __syncthreads();

#pragma unroll
    for (int kk = 0; kk < 2; ++kk) {
      int j = kk*4 + q4;                 // logical 16B chunk within row
      bf16x8 af[4], bfr[8];
#pragma unroll
      for (int mi=0; mi<4; ++mi){
        int row = wm + mi*16 + fm;
        af[mi] = *(const bf16x8*)&Als[row*GK + ((j ^ row) & 7)*8];
      }
#pragma unroll
      for (int ni=0; ni<8; ++ni){
        int row = wn + ni*16 + fm;
        bfr[ni] = *(const bf16x8*)&Bls[row*GK + ((j ^ row) & 7)*8];
      }
#pragma unroll
      for (int mi=0; mi<4; ++mi)
#pragma unroll
        for (int ni=0; ni<8; ++ni)
          acc[mi][ni] = __builtin_amdgcn_mfma_f32_16x16x32_bf16(af[mi], bfr[ni], acc[mi][ni], 0, 0, 0);
    }
    __syncthreads();
  }

  int seg = col0 >> 8;                   // col0 is 256-aligned: block maps to one output
  int cn = lane & 15, cr = (lane >> 4) * 4;
#pragma unroll
  for (int ni=0; ni<8; ++ni){
    int col  = wn + ni*16 + cn;          // 0..255 within segment
    int gcol = col0 + col;
    float bb = bias[gcol];
#pragma unroll
    for (int mi=0; mi<4; ++mi){
#pragma unroll
      for (int r=0; r<4; ++r){
        int row = row0 + wm + mi*16 + cr + r;
        if (row < M){
          float v = acc[mi][ni][r] + bb;
          if (seg == 0)      Cf [(size_t)row*256 + col] = v;
          else if (seg == 1) Cx1[(size_t)row*256 + col] = f2b(v);
          else               Cx2[(size_t)row*256 + col] = f2b(v);
        }
      }
    }
  }
}

// ---------------- CSR build by dst ----------------
__global__ void hist_kernel(const int* __restrict__ ei, int* __restrict__ deg){
  int e = blockIdx.x*blockDim.x + threadIdx.x;
  if (e < EE) atomicAdd(&deg[ei[EE + e]], 1);
}

// parallel 3-phase scan
__global__ __launch_bounds__(1024) void scan1_kernel(const int* __restrict__ deg,
                                                     int* __restrict__ incl, int* __restrict__ bsum){
  __shared__ int wsums[16];
  int t = threadIdx.x, lane = t & 63, w = t >> 6;
  int i = blockIdx.x*1024 + t;
  int v = (i < NN) ? deg[i] : 0;
  int sc = v;
#pragma unroll
  for (int off = 1; off < 64; off <<= 1) {
    int o = __shfl_up(sc, off, 64);
    if (lane >= off) sc += o;
  }
  if (lane == 63) wsums[w] = sc;
  __syncthreads();
  if (w == 0) {
    int ws = (lane < 16) ? wsums[lane] : 0;
#pragma unroll
    for (int off = 1; off < 16; off <<= 1) {
      int o = __shfl_up(ws, off, 64);
      if (lane >= off) ws += o;
    }
    if (lane < 16) wsums[lane] = ws;
  }
  __syncthreads();
  int woff = (w > 0) ? wsums[w-1] : 0;
  if (i < NN) incl[i] = sc + woff;
  if (t == 1023) bsum[blockIdx.x] = woff + sc;
}

__global__ void scan2_kernel(int* __restrict__ bsum, int nblk){
  int lane = threadIdx.x;
  int v = (lane < nblk) ? bsum[lane] : 0;
#pragma unroll
  for (int off = 1; off < 64; off <<= 1) {
    int o = __shfl_up(v, off, 64);
    if (lane >= off) v += o;
  }
  if (lane < nblk) bsum[lane] = v;
}

__global__ __launch_bounds__(1024) void scan3_kernel(const int* __restrict__ incl,
                                                     const int* __restrict__ deg,
                                                     const int* __restrict__ bsum,
                                                     int* __restrict__ rowptr, int* __restrict__ cursor,
                                                     int nblk){
  int i = blockIdx.x*1024 + threadIdx.x;
  if (i < NN) {
    int b = blockIdx.x;
    int prev = (b > 0) ? bsum[b-1] : 0;
    int ex = prev + incl[i] - deg[i];
    rowptr[i] = ex;
    cursor[i] = ex;
  }
  if (i == 0) rowptr[NN] = bsum[nblk-1];
}

// scatter: place edge into its dst bin. 8B per edge ({src, edge_id}).
__global__ void scatter_kernel(const int* __restrict__ ei,
                               int* __restrict__ cursor,
                               uint2* __restrict__ sedata){
  int e = blockIdx.x*blockDim.x + threadIdx.x;
  if (e >= EE) return;
  int s = ei[e];
  int d = ei[EE + e];
  int pos = atomicAdd(&cursor[d], 1);
  uint2 se; se.x = (unsigned)s; se.y = (unsigned)e;
  sedata[pos] = se;
}

// ---------------- per-node attention: batched 8-deep gather pipeline + packed fp32 ----------------
// (1 wave per node, 64 lanes x 4 channels, readlane-broadcast edge scalars,
//  8-deep flat gather pipeline. Geometry recomputed from norm_uv (L2-resident).
//  Single dispatch — splitting into sequential quarters cost +46 us (r8).)
#define LOAD8(Q, B0)                                               \
  if ((B0) < cnt) {                                                \
    _Pragma("unroll")                                              \
    for (int t = 0; t < 8; ++t) {                                  \
      int sj = rlane_i(s, ((B0) + t) & 63);                        \
      Q[t] = *(const uint2*)(xlp + ((size_t)sj << 8));             \
    }                                                              \
  }

#define PROC8(Q, B0)                                               \
  _Pragma("unroll")                                                \
  for (int t = 0; t < 8; ++t) {                                    \
    int j = (B0) + t;                                              \
    if (j < cnt) {                                                 \
      float ruj = rlane_f(edx, j);                                 \
      float rvj = rlane_f(edy, j);                                 \
      float dj  = rlane_f(edz, j);                                 \
      f32x2 x01 = unpk(Q[t].x), x23 = unpk(Q[t].y);                \
      f32x2 t01 = fma2(set2(ruj), we0a, xr01);                     \
      t01 = fma2(set2(rvj), we1a, t01);                            \
      t01 = fma2(set2(dj),  we2a, t01);                            \
      t01 = t01 + x01;                                             \
      f32x2 t23 = fma2(set2(ruj), we0b, xr23);                     \
      t23 = fma2(set2(rvj), we1b, t23);                            \
      t23 = fma2(set2(dj),  we2b, t23);                            \
      t23 = t23 + x23;                                             \
      t01 = max2(t01, t01*0.2f);                                   \
      t23 = max2(t23, t23*0.2f);                                   \
      f32x2 pd = t01*atta;                                         \
      pd = fma2(t23, attb, pd);                                    \
      float p = pd.x + pd.y;                                       \
      p += __shfl_xor(p, 1, 64);                                   \
      p += __shfl_xor(p, 2, 64);                                   \
      p += __shfl_xor(p, 4, 64);                                   \
      p += __shfl_xor(p, 8, 64);                                   \
      float exv = __expf(p);                                       \
      denom += exv;                                                \
      int ej = rlane_i(e, j);                                      \
      if ((lane & 15) == 0) alpha_out[(size_t)ej*4 + head] = exv;  \
      f32x2 ex2 = set2(exv);                                       \
      agg01 = fma2(ex2, x01, agg01);                               \
      agg23 = fma2(ex2, x23, agg23);                               \
    }                                                              \
  }

__global__ __launch_bounds__(128) void node_attn_kernel(
    const uint2* __restrict__ sedata, const float* __restrict__ nuv,
    const unsigned short* __restrict__ xl, const unsigned short* __restrict__ xr,
    const float* __restrict__ We, const float* __restrict__ att,
    const float* __restrict__ cbias, const float* __restrict__ gamma,
    const float* __restrict__ beta,
    const int* __restrict__ rowptr,
    const float* __restrict__ identity,
    float* __restrict__ alpha_out, float* __restrict__ denom_buf,
    unsigned short* __restrict__ hbuf)
{
  int wid  = threadIdx.x >> 6;
  int lane = threadIdx.x & 63;
  int v = blockIdx.x*2 + wid;
  if (v >= NN) return;
  int c0 = lane*4;
  int head = lane >> 4;

  f32x2 we0a, we0b, we1a, we1b, we2a, we2b, atta, attb;
  we0a.x = We[c0];       we0a.y = We[c0+1];       we0b.x = We[c0+2];       we0b.y = We[c0+3];
  we1a.x = We[256+c0];   we1a.y = We[256+c0+1];   we1b.x = We[256+c0+2];   we1b.y = We[256+c0+3];
  we2a.x = We[512+c0];   we2a.y = We[512+c0+1];   we2b.x = We[512+c0+2];   we2b.y = We[512+c0+3];
  atta.x = att[c0];      atta.y = att[c0+1];      attb.x = att[c0+2];      attb.y = att[c0+3];
  uint2 xrq = *(const uint2*)(xr + (size_t)v*256 + c0);
  f32x2 xr01 = unpk(xrq.x), xr23 = unpk(xrq.y);
  const unsigned short* xlp = xl + c0;
  float2 duv = *(const float2*)(nuv + 2*(size_t)v);

  int rs = rowptr[v], re = rowptr[v+1];
  int deg = re - rs;

  float denom = 0.f;
  f32x2 agg01 = set2(0.f), agg23 = set2(0.f);

  for (int base = 0; base < deg; base += 64) {
    int cnt = min(64, deg - base);
    int s = 0, e = 0;
    if (lane < cnt) {
      uint2 se = sedata[rs + base + lane];
      s = (int)se.x;
      e = (int)se.y;
    }
    // recompute geometry (bit-identical to old scatter-side math)
    float2 suv = *(const float2*)(nuv + 2*(size_t)s);
    float edx = duv.x - suv.x;
    float edy = duv.y - suv.y;
    float edz = sqrtf(edx*edx + edy*edy);

    uint2 qa[8], qb[8];
    LOAD8(qa, 0);
    for (int b0 = 0; b0 < cnt; b0 += 16) {
      LOAD8(qb, b0 + 8);
      PROC8(qa, b0);
      LOAD8(qa, b0 + 16);
      PROC8(qb, b0 + 8);
    }
  }

  float rdenom = 1.0f / (denom + 1e-16f);
  if ((lane & 15) == 0) denom_buf[(size_t)v*4 + head] = denom;

  float a0 = agg01.x*rdenom + cbias[c0];
  float a1 = agg01.y*rdenom + cbias[c0+1];
  float a2 = agg23.x*rdenom + cbias[c0+2];
  float a3 = agg23.y*rdenom + cbias[c0+3];

  float ps  = a0 + a1 + a2 + a3;
  float ps2 = a0*a0 + a1*a1 + a2*a2 + a3*a3;
#pragma unroll
  for (int off = 1; off < 64; off <<= 1) {
    ps  += __shfl_xor(ps,  off, 64);
    ps2 += __shfl_xor(ps2, off, 64);
  }
  float mu  = ps  * (1.0f/256.0f);
  float var = ps2 * (1.0f/256.0f) - mu*mu;
  float rstd = rsqrtf(var + 1e-5f);
  float4 g  = ld4(gamma + c0);
  float4 b  = ld4(beta  + c0);
  float4 idv = ld4(identity + (size_t)v*256 + c0);
  float y0 = (a0 - mu)*rstd*g.x + b.x;
  float y1 = (a1 - mu)*rstd*g.y + b.y;
  float y2 = (a2 - mu)*rstd*g.z + b.z;
  float y3 = (a3 - mu)*rstd*g.w + b.w;
  y0 = y0 / (1.0f + __expf(-y0)) + idv.x;
  y1 = y1 / (1.0f + __expf(-y1)) + idv.y;
  y2 = y2 / (1.0f + __expf(-y2)) + idv.z;
  y3 = y3 / (1.0f + __expf(-y3)) + idv.w;
  ushort4 hq; hq.x=f2b(y0); hq.y=f2b(y1); hq.z=f2b(y2); hq.w=f2b(y3);
  *(ushort4*)(hbuf + (size_t)v*256 + c0) = hq;
}

// ---------------- finalize alpha: alpha[e,h] = ex[e,h] / (denom[dst,h]+1e-16) ----------------
__global__ void alpha_fin_kernel(const int* __restrict__ ei, const float* __restrict__ denom_buf,
                                 float* __restrict__ alpha)
{
  int e = blockIdx.x*blockDim.x + threadIdx.x;
  if (e >= EE) return;
  int d = ei[EE + e];
  float4 dn = ld4(denom_buf + (size_t)d*4);
  float4 a = ld4(alpha + (size_t)e*4);
  a.x /= (dn.x + 1e-16f);
  a.y /= (dn.y + 1e-16f);
  a.z /= (dn.z + 1e-16f);
  a.w /= (dn.w + 1e-16f);
  *(float4*)(alpha + (size_t)e*4) = a;
}

extern "C" void kernel_launch(void* const* d_in, const int* in_sizes, int n_in,
                              void* d_out, int out_size, void* d_ws, size_t ws_size,
                              hipStream_t stream)
{
  const float* x      = (const float*)d_in[0];
  const float* kpts   = (const float*)d_in[1];
  const float* pts3d  = (const float*)d_in[2];
  const int*   ei     = (const int*)d_in[3];
  const float* W1     = (const float*)d_in[4];
  const float* b1     = (const float*)d_in[5];
  const float* W2     = (const float*)d_in[6];
  const float* b2     = (const float*)d_in[7];
  const float* Wres   = (const float*)d_in[8];
  const float* bres   = (const float*)d_in[9];
  const float* Wl     = (const float*)d_in[10];
  const float* bl     = (const float*)d_in[11];
  const float* Wr     = (const float*)d_in[12];
  const float* br     = (const float*)d_in[13];
  const float* We     = (const float*)d_in[14];
  const float* att    = (const float*)d_in[15];
  const float* cbias  = (const float*)d_in[16];
  const float* gamma  = (const float*)d_in[17];
  const float* beta   = (const float*)d_in[18];
  const float* Wp     = (const float*)d_in[19];
  const float* bp     = (const float*)d_in[20];

  float* out       = (float*)d_out;
  float* alpha_out = out + (size_t)NN*HIDC;

  // workspace layout (units: float elements) — ~153 MB
  float* wsf = (float*)d_ws;
  float*          identity = wsf;                               // 12,800,000 f
  unsigned short* xl       = (unsigned short*)(wsf + 12800000); // 12,812,288 us
  unsigned short* xr       = (unsigned short*)(wsf + 19206144);
  unsigned short* nodex    = (unsigned short*)(wsf + 25612288); // 16,015,360 us
  unsigned short* hbuf     = (unsigned short*)(wsf + 25612288); // alias nodex (dead after gemm3)
  unsigned short* wt       = (unsigned short*)(wsf + 33619968); // 311,296 us
  float*          biascat  = wsf + 33775616;                    // 768 f
  float*          denomb   = wsf + 33776384;                    // 200,000 f
  uint2*          sedata   = (uint2*)(wsf + 33976384);          // 800,000 uint2 (1.6M f)
  float*          nuv      = wsf + 35576384;                    // 100,000 f (norm_uv)
  int*            incl     = (int*)(wsf + 37176384);            // 800,000 i scratch
  int*            deg      = (int*)(wsf + 37976384);            // 50,000 i
  int*            rowptr   = (int*)(wsf + 38026384);            // 50,001 i
  int*            cursor   = (int*)(wsf + 38076385);            // 50,000 i
  int*            bsum     = (int*)(wsf + 38126385);            // 64 i

  unsigned short* wtcat = wt;            // 768 x 320 (Wres_T | Wl_T | Wr_T)
  unsigned short* wtp   = wt + 245760;   // 256 x 256

  cvt_x_kernel<<<12500, 256, 0, stream>>>(x, nodex);
  node_mlp_kernel<<<(NN+255)/256, 256, 0, stream>>>(kpts, pts3d, W1, b1, W2, b2, nodex, nuv);
  cvt_w_kernel<<<1219, 256, 0, stream>>>(Wres, Wl, Wr, Wp, bres, bl, br, wt, biascat);

  // fused triple GEMM: [identity | x_l | x_r] = nodex @ [Wres|Wl|Wr] + bias
  // 256-wide col tiles: 3 col-blocks, each maps to exactly one output segment
  dim3 g3(3, NPAD/128);
  mfma_gemm_kernel<<<g3, 256, 0, stream>>>(nodex, wtcat, biascat, identity, xl, xr, NN, INCH);

  hipMemsetAsync(deg, 0, NN*sizeof(int), stream);
  hist_kernel<<<(EE+255)/256, 256, 0, stream>>>(ei, deg);
  int nblk = (NN + 1023) / 1024;   // 49
  scan1_kernel<<<nblk, 1024, 0, stream>>>(deg, incl, bsum);
  scan2_kernel<<<1, 64, 0, stream>>>(bsum, nblk);
  scan3_kernel<<<nblk, 1024, 0, stream>>>(incl, deg, bsum, rowptr, cursor, nblk);
  scatter_kernel<<<(EE+255)/256, 256, 0, stream>>>(ei, cursor, sedata);

  node_attn_kernel<<<(NN+1)/2, 128, 0, stream>>>(sedata, nuv, xl, xr, We, att,
                                                 cbias, gamma, beta,
                                                 rowptr, identity,
                                                 alpha_out, denomb, hbuf);
  alpha_fin_kernel<<<(EE+255)/256, 256, 0, stream>>>(ei, denomb, alpha_out);

  // output projection: single 256-wide col tile — A read exactly once
  dim3 g1(1, NPAD/128);
  mfma_gemm_kernel<<<g1, 256, 0, stream>>>(hbuf, wtp, bp, out, nullptr, nullptr, NN, HIDC);
}

// Round 10
// 535.761 us; speedup vs baseline: 1.0883x; 1.0386x over previous
//
#include <hip/hip_runtime.h>
#include <math.h>

#define NN 50000
#define NPAD 50048
#define EE 800000
#define HIDC 256
#define INCH 320

typedef __attribute__((ext_vector_type(8))) short bf16x8;
typedef __attribute__((ext_vector_type(4))) float f32x4;
typedef __attribute__((ext_vector_type(2))) float f32x2;

static __device__ __forceinline__ float4 ld4(const float* p){ return *(const float4*)p; }

static __device__ __forceinline__ unsigned short f2b(float f){
  union { float f; unsigned u; } v; v.f = f;
  unsigned r = v.u + 0x7fffu + ((v.u >> 16) & 1u);
  return (unsigned short)(r >> 16);
}
static __device__ __forceinline__ float b2f(unsigned short u){
  union { unsigned u; float f; } v; v.u = ((unsigned)u) << 16; return v.f;
}
static __device__ __forceinline__ float rlane_f(float v, int l){
  return __uint_as_float(__builtin_amdgcn_readlane(__float_as_uint(v), l));
}
static __device__ __forceinline__ int rlane_i(int v, int l){
  return __builtin_amdgcn_readlane(v, l);
}
// unpack two bf16 packed in a u32 -> 2 floats (lo = .x, hi = .y)
static __device__ __forceinline__ f32x2 unpk(unsigned u){
  f32x2 r;
  r.x = __uint_as_float(u << 16);
  r.y = __uint_as_float(u & 0xffff0000u);
  return r;
}
static __device__ __forceinline__ f32x2 fma2(f32x2 a, f32x2 b, f32x2 c){
  return __builtin_elementwise_fma(a, b, c);
}
static __device__ __forceinline__ f32x2 max2(f32x2 a, f32x2 b){
  return __builtin_elementwise_max(a, b);
}
static __device__ __forceinline__ f32x2 set2(float v){ f32x2 r; r.x = v; r.y = v; return r; }

typedef const __attribute__((address_space(1))) unsigned int* gas_u32;
typedef __attribute__((address_space(3))) unsigned int* las_u32;
static __device__ __forceinline__ void gload_lds16(const void* g, void* l){
  __builtin_amdgcn_global_load_lds((gas_u32)g, (las_u32)l, 16, 0, 0);
}

// ---------------- convert x (fp32 50000x256) into node_x bf16 (NPAD x 320, cols 0..255) ----------------
__global__ void cvt_x_kernel(const float* __restrict__ x, unsigned short* __restrict__ nodex)
{
  int t = blockIdx.x*blockDim.x + threadIdx.x;
  int row = t >> 6;
  if (row >= NN) return;
  int c4 = (t & 63) * 4;
  float4 v = ld4(x + (size_t)row*256 + c4);
  ushort4 o;
  o.x = f2b(v.x); o.y = f2b(v.y); o.z = f2b(v.z); o.w = f2b(v.w);
  *(ushort4*)(nodex + (size_t)row*320 + c4) = o;
}

// ---------------- node positional MLP: writes bf16 into node_x cols 256..319 + norm_uv table ----------------
__global__ void node_mlp_kernel(const float* __restrict__ kpts,
                                const float* __restrict__ pts3d,
                                const float* __restrict__ W1, const float* __restrict__ b1,
                                const float* __restrict__ W2, const float* __restrict__ b2,
                                unsigned short* __restrict__ nodex,
                                float* __restrict__ nuv)
{
  int i = blockIdx.x*blockDim.x + threadIdx.x;
  if (i >= NN) return;
  float u = kpts[2*i]   * (1.0f/1216.0f);
  float v = kpts[2*i+1] * (1.0f/352.0f);
  float d = pts3d[3*i+2];
  float2 uv; uv.x = u; uv.y = v;
  *(float2*)(nuv + 2*i) = uv;
  float h[32];
#pragma unroll
  for (int j=0;j<32;++j){
    float t = u*W1[j] + v*W1[32+j] + d*W1[64+j] + b1[j];
    h[j] = t / (1.0f + __expf(-t));   // silu
  }
  for (int o=0;o<64;o+=4){
    float s0=b2[o], s1=b2[o+1], s2=b2[o+2], s3=b2[o+3];
#pragma unroll
    for (int j=0;j<32;++j){
      float hj = h[j];
      const float* w = W2 + j*64 + o;
      s0 += hj*w[0]; s1 += hj*w[1]; s2 += hj*w[2]; s3 += hj*w[3];
    }
    ushort4 r; r.x=f2b(s0); r.y=f2b(s1); r.z=f2b(s2); r.w=f2b(s3);
    *(ushort4*)(nodex + (size_t)i*320 + 256 + o) = r;
  }
}

// ---------------- convert + transpose weights to bf16 N-major (K contiguous) + bias concat ----------------
__global__ void cvt_w_kernel(const float* __restrict__ Wres, const float* __restrict__ Wl,
                             const float* __restrict__ Wr,   const float* __restrict__ Wp,
                             const float* __restrict__ bres, const float* __restrict__ bl,
                             const float* __restrict__ br,
                             unsigned short* __restrict__ wt, float* __restrict__ biascat)
{
  int t = blockIdx.x*blockDim.x + threadIdx.x;   // 312064 threads
  if (t < 245760) {
    int which = t / 81920;
    int rem = t % 81920;
    int n = rem / 320, k = rem % 320;
    const float* W = (which == 0) ? Wres : (which == 1) ? Wl : Wr;
    wt[(size_t)which*81920 + rem] = f2b(W[(size_t)k*256 + n]);
  } else if (t < 311296) {
    int r = t - 245760;
    int n = r / 256, k = r % 256;
    wt[245760 + r] = f2b(Wp[(size_t)k*256 + n]);
  } else {
    int r = t - 311296;   // 0..767
    const float* src = (r < 256) ? bres : (r < 512) ? bl : br;
    biascat[r] = src[r & 255];
  }
}

// ---------------- bf16 MFMA GEMM: C(M,Nt) = A(M,K) @ BT(Nt,K)^T + bias ----------------
// 128x128 tile (proven best: r9's 128x256 regressed +19us — latency-bound GEMM
// wants TLP, not wider tiles). GK=64 + XOR slot-swizzle.
// 1-D grid + XCD panel grouping: all `ncols` col-blocks of a row-panel get
// bids congruent mod 8 -> same XCD -> A-panel fetched from HBM once, then L2
// (r8 FETCH showed 97MB = 3x compulsory A traffic from cross-XCD refetch).
// Pure index permutation: FP math and output addresses bit-identical.
#define GK 64
__global__ __launch_bounds__(256) void mfma_gemm_kernel(
    const unsigned short* __restrict__ A,
    const unsigned short* __restrict__ BT,
    const float* __restrict__ bias,
    float* __restrict__ Cf,
    unsigned short* __restrict__ Cx1,
    unsigned short* __restrict__ Cx2,
    int M, int K, int npan, int ncols)
{
  __shared__ unsigned short Als[128*GK];   // 16 KB
  __shared__ unsigned short Bls[128*GK];   // 16 KB
  int tid = threadIdx.x;
  int lane = tid & 63, wave = tid >> 6;
  int wm = (wave >> 1) * 64, wn = (wave & 1) * 64;

  // ---- bid -> (panel p, col-block c) with panel->XCD co-location ----
  int bid = blockIdx.x;
  int fullp = (npan >> 3) << 3;        // panels covered by full groups of 8
  int nfull = fullp * ncols;
  int p, c;
  if (bid < nfull) {
    int g  = bid / (8*ncols);          // group of 8 panels
    int r  = bid - g*(8*ncols);
    c  = r >> 3;                       // r = c*8 + pe  ->  bid % 8 == pe
    p  = g*8 + (r & 7);
  } else {
    int r = bid - nfull;
    int tail = npan - fullp;           // 1..7
    p = fullp + r % tail;
    c = r / tail;
  }
  int row0 = p * 128, col0 = c * 128;

  f32x4 acc[4][4];
#pragma unroll
  for (int i=0;i<4;++i)
#pragma unroll
    for (int j=0;j<4;++j){ acc[i][j].x=0.f; acc[i][j].y=0.f; acc[i][j].z=0.f; acc[i][j].w=0.f; }

  int fm = lane & 15;
  int q4 = lane >> 4;          // quarter-wave index 0..3

  for (int k0 = 0; k0 < K; k0 += GK) {
#pragma unroll
    for (int it = 0; it < 4; ++it) {
      int cgl = it*256 + tid;            // chunk id 0..1023 (16B chunks)
      int r = cgl >> 3;                  // tile row 0..127
      int kb = ((cgl ^ r) & 7) * 8;      // swizzled k-chunk (elements)
      gload_lds16(A  + (size_t)(row0 + r)*K + k0 + kb, Als + (it*256 + wave*64)*8);
      gload_lds16(BT + (size_t)(col0 + r)*K + k0 + kb, Bls + (it*256 + wave*64)*8);
    }
    __syncthreads();

#pragma unroll
    for (int kk = 0; kk < 2; ++kk) {
      int j = kk*4 + q4;                 // logical 16B chunk within row
      bf16x8 af[4], bfr[4];
#pragma unroll
      for (int mi=0; mi<4; ++mi){
        int row = wm + mi*16 + fm;
        af[mi] = *(const bf16x8*)&Als[row*GK + ((j ^ row) & 7)*8];
      }
#pragma unroll
      for (int ni=0; ni<4; ++ni){
        int row = wn + ni*16 + fm;
        bfr[ni] = *(const bf16x8*)&Bls[row*GK + ((j ^ row) & 7)*8];
      }
#pragma unroll
      for (int mi=0; mi<4; ++mi)
#pragma unroll
        for (int ni=0; ni<4; ++ni)
          acc[mi][ni] = __builtin_amdgcn_mfma_f32_16x16x32_bf16(af[mi], bfr[ni], acc[mi][ni], 0, 0, 0);
    }
    __syncthreads();
  }

  int seg = col0 >> 8;
  int colbase = col0 - seg*256;
  int cn = lane & 15, cr = (lane >> 4) * 4;
#pragma unroll
  for (int ni=0; ni<4; ++ni){
    int gcol = col0 + wn + ni*16 + cn;
    int col  = colbase + wn + ni*16 + cn;
    float bb = bias[gcol];
#pragma unroll
    for (int mi=0; mi<4; ++mi){
#pragma unroll
      for (int r=0; r<4; ++r){
        int row = row0 + wm + mi*16 + cr + r;
        if (row < M){
          float v = acc[mi][ni][r] + bb;
          if (seg == 0)      Cf [(size_t)row*256 + col] = v;
          else if (seg == 1) Cx1[(size_t)row*256 + col] = f2b(v);
          else               Cx2[(size_t)row*256 + col] = f2b(v);
        }
      }
    }
  }
}

// ---------------- CSR build by dst ----------------
__global__ void hist_kernel(const int* __restrict__ ei, int* __restrict__ deg){
  int e = blockIdx.x*blockDim.x + threadIdx.x;
  if (e < EE) atomicAdd(&deg[ei[EE + e]], 1);
}

// parallel 3-phase scan
__global__ __launch_bounds__(1024) void scan1_kernel(const int* __restrict__ deg,
                                                     int* __restrict__ incl, int* __restrict__ bsum){
  __shared__ int wsums[16];
  int t = threadIdx.x, lane = t & 63, w = t >> 6;
  int i = blockIdx.x*1024 + t;
  int v = (i < NN) ? deg[i] : 0;
  int sc = v;
#pragma unroll
  for (int off = 1; off < 64; off <<= 1) {
    int o = __shfl_up(sc, off, 64);
    if (lane >= off) sc += o;
  }
  if (lane == 63) wsums[w] = sc;
  __syncthreads();
  if (w == 0) {
    int ws = (lane < 16) ? wsums[lane] : 0;
#pragma unroll
    for (int off = 1; off < 16; off <<= 1) {
      int o = __shfl_up(ws, off, 64);
      if (lane >= off) ws += o;
    }
    if (lane < 16) wsums[lane] = ws;
  }
  __syncthreads();
  int woff = (w > 0) ? wsums[w-1] : 0;
  if (i < NN) incl[i] = sc + woff;
  if (t == 1023) bsum[blockIdx.x] = woff + sc;
}

__global__ void scan2_kernel(int* __restrict__ bsum, int nblk){
  int lane = threadIdx.x;
  int v = (lane < nblk) ? bsum[lane] : 0;
#pragma unroll
  for (int off = 1; off < 64; off <<= 1) {
    int o = __shfl_up(v, off, 64);
    if (lane >= off) v += o;
  }
  if (lane < nblk) bsum[lane] = v;
}

__global__ __launch_bounds__(1024) void scan3_kernel(const int* __restrict__ incl,
                                                     const int* __restrict__ deg,
                                                     const int* __restrict__ bsum,
                                                     int* __restrict__ rowptr, int* __restrict__ cursor,
                                                     int nblk){
  int i = blockIdx.x*1024 + threadIdx.x;
  if (i < NN) {
    int b = blockIdx.x;
    int prev = (b > 0) ? bsum[b-1] : 0;
    int ex = prev + incl[i] - deg[i];
    rowptr[i] = ex;
    cursor[i] = ex;
  }
  if (i == 0) rowptr[NN] = bsum[nblk-1];
}

// scatter: place edge into its dst bin. 8B per edge ({src, edge_id}).
__global__ void scatter_kernel(const int* __restrict__ ei,
                               int* __restrict__ cursor,
                               uint2* __restrict__ sedata){
  int e = blockIdx.x*blockDim.x + threadIdx.x;
  if (e >= EE) return;
  int s = ei[e];
  int d = ei[EE + e];
  int pos = atomicAdd(&cursor[d], 1);
  uint2 se; se.x = (unsigned)s; se.y = (unsigned)e;
  sedata[pos] = se;
}

// ---------------- per-node attention: batched 8-deep gather pipeline + packed fp32 ----------------
// (1 wave per node, 64 lanes x 4 channels, readlane-broadcast edge scalars,
//  8-deep flat gather pipeline. Geometry recomputed from norm_uv (L2-resident).
//  Single dispatch — splitting into sequential quarters cost +46 us (r8).)
#define LOAD8(Q, B0)                                               \
  if ((B0) < cnt) {                                                \
    _Pragma("unroll")                                              \
    for (int t = 0; t < 8; ++t) {                                  \
      int sj = rlane_i(s, ((B0) + t) & 63);                        \
      Q[t] = *(const uint2*)(xlp + ((size_t)sj << 8));             \
    }                                                              \
  }

#define PROC8(Q, B0)                                               \
  _Pragma("unroll")                                                \
  for (int t = 0; t < 8; ++t) {                                    \
    int j = (B0) + t;                                              \
    if (j < cnt) {                                                 \
      float ruj = rlane_f(edx, j);                                 \
      float rvj = rlane_f(edy, j);                                 \
      float dj  = rlane_f(edz, j);                                 \
      f32x2 x01 = unpk(Q[t].x), x23 = unpk(Q[t].y);                \
      f32x2 t01 = fma2(set2(ruj), we0a, xr01);                     \
      t01 = fma2(set2(rvj), we1a, t01);                            \
      t01 = fma2(set2(dj),  we2a, t01);                            \
      t01 = t01 + x01;                                             \
      f32x2 t23 = fma2(set2(ruj), we0b, xr23);                     \
      t23 = fma2(set2(rvj), we1b, t23);                            \
      t23 = fma2(set2(dj),  we2b, t23);                            \
      t23 = t23 + x23;                                             \
      t01 = max2(t01, t01*0.2f);                                   \
      t23 = max2(t23, t23*0.2f);                                   \
      f32x2 pd = t01*atta;                                         \
      pd = fma2(t23, attb, pd);                                    \
      float p = pd.x + pd.y;                                       \
      p += __shfl_xor(p, 1, 64);                                   \
      p += __shfl_xor(p, 2, 64);                                   \
      p += __shfl_xor(p, 4, 64);                                   \
      p += __shfl_xor(p, 8, 64);                                   \
      float exv = __expf(p);                                       \
      denom += exv;                                                \
      int ej = rlane_i(e, j);                                      \
      if ((lane & 15) == 0) alpha_out[(size_t)ej*4 + head] = exv;  \
      f32x2 ex2 = set2(exv);                                       \
      agg01 = fma2(ex2, x01, agg01);                               \
      agg23 = fma2(ex2, x23, agg23);                               \
    }                                                              \
  }

__global__ __launch_bounds__(128) void node_attn_kernel(
    const uint2* __restrict__ sedata, const float* __restrict__ nuv,
    const unsigned short* __restrict__ xl, const unsigned short* __restrict__ xr,
    const float* __restrict__ We, const float* __restrict__ att,
    const float* __restrict__ cbias, const float* __restrict__ gamma,
    const float* __restrict__ beta,
    const int* __restrict__ rowptr,
    const float* __restrict__ identity,
    float* __restrict__ alpha_out, float* __restrict__ denom_buf,
    unsigned short* __restrict__ hbuf)
{
  int wid  = threadIdx.x >> 6;
  int lane = threadIdx.x & 63;
  int v = blockIdx.x*2 + wid;
  if (v >= NN) return;
  int c0 = lane*4;
  int head = lane >> 4;

  f32x2 we0a, we0b, we1a, we1b, we2a, we2b, atta, attb;
  we0a.x = We[c0];       we0a.y = We[c0+1];       we0b.x = We[c0+2];       we0b.y = We[c0+3];
  we1a.x = We[256+c0];   we1a.y = We[256+c0+1];   we1b.x = We[256+c0+2];   we1b.y = We[256+c0+3];
  we2a.x = We[512+c0];   we2a.y = We[512+c0+1];   we2b.x = We[512+c0+2];   we2b.y = We[512+c0+3];
  atta.x = att[c0];      atta.y = att[c0+1];      attb.x = att[c0+2];      attb.y = att[c0+3];
  uint2 xrq = *(const uint2*)(xr + (size_t)v*256 + c0);
  f32x2 xr01 = unpk(xrq.x), xr23 = unpk(xrq.y);
  const unsigned short* xlp = xl + c0;
  float2 duv = *(const float2*)(nuv + 2*(size_t)v);

  int rs = rowptr[v], re = rowptr[v+1];
  int deg = re - rs;

  float denom = 0.f;
  f32x2 agg01 = set2(0.f), agg23 = set2(0.f);

  for (int base = 0; base < deg; base += 64) {
    int cnt = min(64, deg - base);
    int s = 0, e = 0;
    if (lane < cnt) {
      uint2 se = sedata[rs + base + lane];
      s = (int)se.x;
      e = (int)se.y;
    }
    // recompute geometry (bit-identical to old scatter-side math)
    float2 suv = *(const float2*)(nuv + 2*(size_t)s);
    float edx = duv.x - suv.x;
    float edy = duv.y - suv.y;
    float edz = sqrtf(edx*edx + edy*edy);

    uint2 qa[8], qb[8];
    LOAD8(qa, 0);
    for (int b0 = 0; b0 < cnt; b0 += 16) {
      LOAD8(qb, b0 + 8);
      PROC8(qa, b0);
      LOAD8(qa, b0 + 16);
      PROC8(qb, b0 + 8);
    }
  }

  float rdenom = 1.0f / (denom + 1e-16f);
  if ((lane & 15) == 0) denom_buf[(size_t)v*4 + head] = denom;

  float a0 = agg01.x*rdenom + cbias[c0];
  float a1 = agg01.y*rdenom + cbias[c0+1];
  float a2 = agg23.x*rdenom + cbias[c0+2];
  float a3 = agg23.y*rdenom + cbias[c0+3];

  float ps  = a0 + a1 + a2 + a3;
  float ps2 = a0*a0 + a1*a1 + a2*a2 + a3*a3;
#pragma unroll
  for (int off = 1; off < 64; off <<= 1) {
    ps  += __shfl_xor(ps,  off, 64);
    ps2 += __shfl_xor(ps2, off, 64);
  }
  float mu  = ps  * (1.0f/256.0f);
  float var = ps2 * (1.0f/256.0f) - mu*mu;
  float rstd = rsqrtf(var + 1e-5f);
  float4 g  = ld4(gamma + c0);
  float4 b  = ld4(beta  + c0);
  float4 idv = ld4(identity + (size_t)v*256 + c0);
  float y0 = (a0 - mu)*rstd*g.x + b.x;
  float y1 = (a1 - mu)*rstd*g.y + b.y;
  float y2 = (a2 - mu)*rstd*g.z + b.z;
  float y3 = (a3 - mu)*rstd*g.w + b.w;
  y0 = y0 / (1.0f + __expf(-y0)) + idv.x;
  y1 = y1 / (1.0f + __expf(-y1)) + idv.y;
  y2 = y2 / (1.0f + __expf(-y2)) + idv.z;
  y3 = y3 / (1.0f + __expf(-y3)) + idv.w;
  ushort4 hq; hq.x=f2b(y0); hq.y=f2b(y1); hq.z=f2b(y2); hq.w=f2b(y3);
  *(ushort4*)(hbuf + (size_t)v*256 + c0) = hq;
}

// ---------------- finalize alpha: alpha[e,h] = ex[e,h] / (denom[dst,h]+1e-16) ----------------
__global__ void alpha_fin_kernel(const int* __restrict__ ei, const float* __restrict__ denom_buf,
                                 float* __restrict__ alpha)
{
  int e = blockIdx.x*blockDim.x + threadIdx.x;
  if (e >= EE) return;
  int d = ei[EE + e];
  float4 dn = ld4(denom_buf + (size_t)d*4);
  float4 a = ld4(alpha + (size_t)e*4);
  a.x /= (dn.x + 1e-16f);
  a.y /= (dn.y + 1e-16f);
  a.z /= (dn.z + 1e-16f);
  a.w /= (dn.w + 1e-16f);
  *(float4*)(alpha + (size_t)e*4) = a;
}

extern "C" void kernel_launch(void* const* d_in, const int* in_sizes, int n_in,
                              void* d_out, int out_size, void* d_ws, size_t ws_size,
                              hipStream_t stream)
{
  const float* x      = (const float*)d_in[0];
  const float* kpts   = (const float*)d_in[1];
  const float* pts3d  = (const float*)d_in[2];
  const int*   ei     = (const int*)d_in[3];
  const float* W1     = (const float*)d_in[4];
  const float* b1     = (const float*)d_in[5];
  const float* W2     = (const float*)d_in[6];
  const float* b2     = (const float*)d_in[7];
  const float* Wres   = (const float*)d_in[8];
  const float* bres   = (const float*)d_in[9];
  const float* Wl     = (const float*)d_in[10];
  const float* bl     = (const float*)d_in[11];
  const float* Wr     = (const float*)d_in[12];
  const float* br     = (const float*)d_in[13];
  const float* We     = (const float*)d_in[14];
  const float* att    = (const float*)d_in[15];
  const float* cbias  = (const float*)d_in[16];
  const float* gamma  = (const float*)d_in[17];
  const float* beta   = (const float*)d_in[18];
  const float* Wp     = (const float*)d_in[19];
  const float* bp     = (const float*)d_in[20];

  float* out       = (float*)d_out;
  float* alpha_out = out + (size_t)NN*HIDC;

  // workspace layout (units: float elements) — ~153 MB
  float* wsf = (float*)d_ws;
  float*          identity = wsf;                               // 12,800,000 f
  unsigned short* xl       = (unsigned short*)(wsf + 12800000); // 12,812,288 us
  unsigned short* xr       = (unsigned short*)(wsf + 19206144);
  unsigned short* nodex    = (unsigned short*)(wsf + 25612288); // 16,015,360 us
  unsigned short* hbuf     = (unsigned short*)(wsf + 25612288); // alias nodex (dead after gemm3)
  unsigned short* wt       = (unsigned short*)(wsf + 33619968); // 311,296 us
  float*          biascat  = wsf + 33775616;                    // 768 f
  float*          denomb   = wsf + 33776384;                    // 200,000 f
  uint2*          sedata   = (uint2*)(wsf + 33976384);          // 800,000 uint2 (1.6M f)
  float*          nuv      = wsf + 35576384;                    // 100,000 f (norm_uv)
  int*            incl     = (int*)(wsf + 37176384);            // 800,000 i scratch
  int*            deg      = (int*)(wsf + 37976384);            // 50,000 i
  int*            rowptr   = (int*)(wsf + 38026384);            // 50,001 i
  int*            cursor   = (int*)(wsf + 38076385);            // 50,000 i
  int*            bsum     = (int*)(wsf + 38126385);            // 64 i

  unsigned short* wtcat = wt;            // 768 x 320 (Wres_T | Wl_T | Wr_T)
  unsigned short* wtp   = wt + 245760;   // 256 x 256

  cvt_x_kernel<<<12500, 256, 0, stream>>>(x, nodex);
  node_mlp_kernel<<<(NN+255)/256, 256, 0, stream>>>(kpts, pts3d, W1, b1, W2, b2, nodex, nuv);
  cvt_w_kernel<<<1219, 256, 0, stream>>>(Wres, Wl, Wr, Wp, bres, bl, br, wt, biascat);

  // fused triple GEMM: [identity | x_l | x_r] = nodex @ [Wres|Wl|Wr] + bias
  // 1-D grid, panel-grouped XCD mapping: 391 panels x 6 col-blocks
  mfma_gemm_kernel<<<391*6, 256, 0, stream>>>(nodex, wtcat, biascat, identity, xl, xr,
                                              NN, INCH, NPAD/128, 6);

  hipMemsetAsync(deg, 0, NN*sizeof(int), stream);
  hist_kernel<<<(EE+255)/256, 256, 0, stream>>>(ei, deg);
  int nblk = (NN + 1023) / 1024;   // 49
  scan1_kernel<<<nblk, 1024, 0, stream>>>(deg, incl, bsum);
  scan2_kernel<<<1, 64, 0, stream>>>(bsum, nblk);
  scan3_kernel<<<nblk, 1024, 0, stream>>>(incl, deg, bsum, rowptr, cursor, nblk);
  scatter_kernel<<<(EE+255)/256, 256, 0, stream>>>(ei, cursor, sedata);

  node_attn_kernel<<<(NN+1)/2, 128, 0, stream>>>(sedata, nuv, xl, xr, We, att,
                                                 cbias, gamma, beta,
                                                 rowptr, identity,
                                                 alpha_out, denomb, hbuf);
  alpha_fin_kernel<<<(EE+255)/256, 256, 0, stream>>>(ei, denomb, alpha_out);

  // output projection: 391 panels x 2 col-blocks
  mfma_gemm_kernel<<<391*2, 256, 0, stream>>>(hbuf, wtp, bp, out, nullptr, nullptr,
                                              NN, HIDC, NPAD/128, 2);
}